// Round 10
// baseline (497.647 us; speedup 1.0000x reference)
//
#include <hip/hip_runtime.h>
#include <math.h>

#define N_NODES 100000
#define E_EDGES 1600000
#define HALF_E  (E_EDGES / 2)

#define NBUCK 256
#define ROWS_PER_BUCKET ((N_NODES + NBUCK - 1) / NBUCK)   // 391
#define EDGES_PER_BLK_A 4096
#define NBLK_A ((E_EDGES + EDGES_PER_BLK_A - 1) / EDGES_PER_BLK_A)  // 391

typedef unsigned short ushort_t;

// ---- bf16 helpers (RNE pack, cheap unpack) ----
__device__ __forceinline__ unsigned bf16_1(float f) {
    unsigned u = __float_as_uint(f);
    return (u + 0x7fffu + ((u >> 16) & 1u)) >> 16;
}
__device__ __forceinline__ unsigned bf16_2(float a, float b) {
    return bf16_1(a) | (bf16_1(b) << 16);
}
__device__ __forceinline__ float bf16_f(ushort_t us) {
    return __uint_as_float(((unsigned)us) << 16);
}

// ============ CSR build (bucketed) ============

__global__ __launch_bounds__(256) void k_bhist(const int* __restrict__ rowIdx,
                                               int* __restrict__ bcnt) {
    __shared__ int c[NBUCK];
    const int tid = threadIdx.x;
    c[tid] = 0;
    __syncthreads();
    for (int e = blockIdx.x * 256 + tid; e < E_EDGES; e += gridDim.x * 256)
        atomicAdd(&c[rowIdx[e] / ROWS_PER_BUCKET], 1);
    __syncthreads();
    if (c[tid]) atomicAdd(&bcnt[tid], c[tid]);
}

__global__ __launch_bounds__(256) void k_bscan256(const int* __restrict__ bcnt,
                                                  int* __restrict__ bbase,
                                                  int* __restrict__ curA,
                                                  int* __restrict__ start) {
    __shared__ int sc[NBUCK];
    const int tid = threadIdx.x;
    int v = bcnt[tid];
    sc[tid] = v;
    __syncthreads();
    for (int st = 1; st < 256; st <<= 1) {
        int t = (tid >= st) ? sc[tid - st] : 0;
        __syncthreads();
        sc[tid] += t;
        __syncthreads();
    }
    int excl = sc[tid] - v;
    bbase[tid] = excl;
    curA[tid] = excl;
    if (tid == 255) bbase[256] = sc[255];
    if (tid == 0) start[N_NODES] = E_EDGES;
}

__global__ __launch_bounds__(256) void k_bucketA(const int* __restrict__ rowIdx,
                                                 const int* __restrict__ colIdx,
                                                 int* __restrict__ cursorA,
                                                 uint2* __restrict__ pairs) {
    __shared__ uint2 stage[EDGES_PER_BLK_A];
    __shared__ unsigned char bmap[EDGES_PER_BLK_A];
    __shared__ int cntL[NBUCK], scanEx[NBUCK], cur[NBUCK], posG[NBUCK];
    const int tid = threadIdx.x;
    const int e0 = blockIdx.x * EDGES_PER_BLK_A;
    const int n = min(EDGES_PER_BLK_A, E_EDGES - e0);

    cntL[tid] = 0;
    __syncthreads();
    for (int i = tid; i < n; i += 256) {
        int b = rowIdx[e0 + i] / ROWS_PER_BUCKET;
        atomicAdd(&cntL[b], 1);
    }
    __syncthreads();
    int myc = cntL[tid];
    scanEx[tid] = myc;
    __syncthreads();
    for (int st = 1; st < 256; st <<= 1) {
        int t = (tid >= st) ? scanEx[tid - st] : 0;
        __syncthreads();
        scanEx[tid] += t;
        __syncthreads();
    }
    int ex = scanEx[tid] - myc;
    __syncthreads();
    scanEx[tid] = ex;
    cur[tid] = ex;
    if (myc) posG[tid] = atomicAdd(&cursorA[tid], myc);
    __syncthreads();
    for (int i = tid; i < n; i += 256) {
        int r = rowIdx[e0 + i];
        int c = colIdx[e0 + i];
        int b = r / ROWS_PER_BUCKET;
        int slot = atomicAdd(&cur[b], 1);
        stage[slot] = make_uint2((unsigned)c, (unsigned)r);
        bmap[slot] = (unsigned char)b;
    }
    __syncthreads();
    for (int i = tid; i < n; i += 256) {
        int b = bmap[i];
        int dst = posG[b] + (i - scanEx[b]);
        pairs[dst] = stage[i];
    }
}

__global__ __launch_bounds__(256) void k_bucketB(const int* __restrict__ bbase,
                                                 const uint2* __restrict__ pairs,
                                                 int* __restrict__ start,
                                                 int* __restrict__ csr) {
    __shared__ int cur[ROWS_PER_BUCKET];
    __shared__ int scn[512];
    const int tid = threadIdx.x;
    const int rowbase = blockIdx.x * ROWS_PER_BUCKET;
    const int nrows = min(ROWS_PER_BUCKET, N_NODES - rowbase);
    for (int i = tid; i < nrows; i += 256) cur[i] = 0;
    __syncthreads();
    const int bBeg = bbase[blockIdx.x];
    const int bEnd = bbase[blockIdx.x + 1];
    for (int i = bBeg + tid; i < bEnd; i += 256)
        atomicAdd(&cur[(int)pairs[i].y - rowbase], 1);
    __syncthreads();
    scn[tid] = (tid < nrows) ? cur[tid] : 0;
    scn[tid + 256] = (tid + 256 < nrows) ? cur[tid + 256] : 0;
    __syncthreads();
    for (int st = 1; st < 512; st <<= 1) {
        int i0 = tid, i1 = tid + 256;
        int t0 = (i0 >= st) ? scn[i0 - st] : 0;
        int t1 = (i1 >= st) ? scn[i1 - st] : 0;
        __syncthreads();
        scn[i0] += t0;
        scn[i1] += t1;
        __syncthreads();
    }
    for (int i = tid; i < nrows; i += 256) {
        int sv = bBeg + scn[i] - cur[i];
        start[rowbase + i] = sv;
        cur[i] = sv;
    }
    __syncthreads();
    for (int i = bBeg + tid; i < bEnd; i += 256) {
        uint2 p = pairs[i];
        int pos = atomicAdd(&cur[(int)p.y - rowbase], 1);
        csr[pos] = (int)p.x;
    }
}

// ============ fused node MLPs ============
// Block = 256 thr = 4 waves; 128 rows/block; each thread owns rows lane and
// 64+lane, 16 output cols (col quarter = wave id, wave-uniform -> s_load
// weights feed 32 FMAs each). One LDS buffer S[128][68] (34.8 KB).

#define SH_STRIDE 68

__device__ __forceinline__ void gemm16x2(const float* xr0, const float* xr1,
                                         const float* __restrict__ wc,
                                         float o0[16], float o1[16],
                                         float s0, float s1) {
#pragma unroll 4
    for (int k = 0; k < 64; ++k) {
        float xk0 = xr0[k] * s0;
        float xk1 = xr1[k] * s1;
        const float* wr = wc + k * 64;
#pragma unroll
        for (int j = 0; j < 16; ++j) {
            o0[j] = fmaf(xk0, wr[j], o0[j]);
            o1[j] = fmaf(xk1, wr[j], o1[j]);
        }
    }
}

// stage contiguous [nrows<=128] x 64 f32 into S (coalesced)
__device__ __forceinline__ void stage128(const float* __restrict__ src,
                                         float S[128][SH_STRIDE], int tid, int nrows) {
#pragma unroll
    for (int i = 0; i < 8; ++i) {
        int idx = tid + i * 256;
        int row = idx >> 4;
        int c4 = (idx & 15) * 4;
        float4 v = (row < nrows) ? *(const float4*)(src + (size_t)row * 64 + c4)
                                 : make_float4(0.f, 0.f, 0.f, 0.f);
        *(float4*)(&S[row][c4]) = v;
    }
}

// stage 64-col slice of x (row stride 128) into S
__device__ __forceinline__ void stageX128(const float* __restrict__ xbase,
                                          float S[128][SH_STRIDE], int tid, int nrows) {
#pragma unroll
    for (int i = 0; i < 8; ++i) {
        int idx = tid + i * 256;
        int row = idx >> 4;
        int c4 = (idx & 15) * 4;
        float4 v = (row < nrows) ? *(const float4*)(xbase + (size_t)row * 128 + c4)
                                 : make_float4(0.f, 0.f, 0.f, 0.f);
        *(float4*)(&S[row][c4]) = v;
    }
}

__device__ __forceinline__ void sh_put2(float S[128][SH_STRIDE], int lane, int co,
                                        const float o0[16], const float o1[16]) {
#pragma unroll
    for (int j4 = 0; j4 < 4; ++j4) {
        *(float4*)(&S[lane][co + j4 * 4]) =
            make_float4(o0[4 * j4], o0[4 * j4 + 1], o0[4 * j4 + 2], o0[4 * j4 + 3]);
        *(float4*)(&S[64 + lane][co + j4 * 4]) =
            make_float4(o1[4 * j4], o1[4 * j4 + 1], o1[4 * j4 + 2], o1[4 * j4 + 3]);
    }
}

__device__ __forceinline__ void g_put16(float* __restrict__ dst, const float o[16]) {
    *(float4*)(dst + 0)  = make_float4(o[0], o[1], o[2], o[3]);
    *(float4*)(dst + 4)  = make_float4(o[4], o[5], o[6], o[7]);
    *(float4*)(dst + 8)  = make_float4(o[8], o[9], o[10], o[11]);
    *(float4*)(dst + 12) = make_float4(o[12], o[13], o[14], o[15]);
}

__device__ __forceinline__ void bf16_put16(ushort_t* __restrict__ dst, const float o[16],
                                           bool relu) {
    float a[16];
#pragma unroll
    for (int j = 0; j < 16; ++j) a[j] = relu ? fmaxf(o[j], 0.0f) : o[j];
    uint4* mv = (uint4*)dst;
    mv[0] = make_uint4(bf16_2(a[0], a[1]), bf16_2(a[2], a[3]),
                       bf16_2(a[4], a[5]), bf16_2(a[6], a[7]));
    mv[1] = make_uint4(bf16_2(a[8], a[9]), bf16_2(a[10], a[11]),
                       bf16_2(a[12], a[13]), bf16_2(a[14], a[15]));
}

// gather agg rows for this block's nodes into S (wave w -> rows [w*32,w*32+32))
__device__ __forceinline__ void gather_to_S(const int* __restrict__ start,
                                            const int* __restrict__ csr,
                                            const ushort_t* __restrict__ msgIn,
                                            float S[128][SH_STRIDE],
                                            int r0, int nrows, int lane, int wid) {
    int rrEnd = min(wid * 32 + 32, nrows);
    for (int rr = wid * 32; rr < rrEnd; ++rr) {
        int rG = r0 + rr;
        int b = start[rG];
        int e0 = start[rG + 1];
        float acc0 = 0.0f, acc1 = 0.0f;
        for (int base = b; base < e0; base += 64) {
            int n = e0 - base;
            if (n > 64) n = 64;
            int c = 0;
            if (base + lane < e0) c = csr[base + lane];
            int j = 0;
            for (; j + 4 <= n; j += 4) {
                int c0 = __shfl(c, j, 64);
                int c1 = __shfl(c, j + 1, 64);
                int c2 = __shfl(c, j + 2, 64);
                int c3 = __shfl(c, j + 3, 64);
                float l0 = bf16_f(msgIn[(size_t)c0 * 64 + lane]);
                float l1 = bf16_f(msgIn[(size_t)c1 * 64 + lane]);
                float l2 = bf16_f(msgIn[(size_t)c2 * 64 + lane]);
                float l3 = bf16_f(msgIn[(size_t)c3 * 64 + lane]);
                acc0 += l0 + l2;
                acc1 += l1 + l3;
            }
            for (; j < n; ++j) {
                int cj = __shfl(c, j, 64);
                acc0 += bf16_f(msgIn[(size_t)cj * 64 + lane]);
            }
        }
        S[rr][lane] = acc0 + acc1;
    }
}

// h = x@w_in+b_in ; msgA = relu(relu(h@m1+b1)@m2+b2)
__global__ __launch_bounds__(256, 4) void k_lin_msg(const float* __restrict__ x,
                                                    const float* __restrict__ w,
                                                    const float* __restrict__ b,
                                                    const float* __restrict__ m1w,
                                                    const float* __restrict__ m1b,
                                                    const float* __restrict__ m2w,
                                                    const float* __restrict__ m2b,
                                                    float* __restrict__ h,
                                                    ushort_t* __restrict__ msgOut) {
    __shared__ float S[128][SH_STRIDE];
    const int tid = threadIdx.x;
    const int lane = tid & 63;
    const int q = __builtin_amdgcn_readfirstlane(tid >> 6);
    const int co = q * 16;
    const int r0 = blockIdx.x * 128;
    const int rA = r0 + lane, rB = r0 + 64 + lane;
    const bool vA = rA < N_NODES, vB = rB < N_NODES;
    const int nrows = min(128, N_NODES - r0);

    float o0[16], o1[16];
#pragma unroll
    for (int j = 0; j < 16; ++j) { o0[j] = b[co + j]; o1[j] = o0[j]; }
    stageX128(x + (size_t)r0 * 128, S, tid, nrows);
    __syncthreads();
    gemm16x2(S[lane], S[64 + lane], w + co, o0, o1, 1.0f, 1.0f);
    __syncthreads();
    stageX128(x + (size_t)r0 * 128 + 64, S, tid, nrows);
    __syncthreads();
    gemm16x2(S[lane], S[64 + lane], w + 64 * 64 + co, o0, o1, 1.0f, 1.0f);
    if (vA) g_put16(h + (size_t)rA * 64 + co, o0);
    if (vB) g_put16(h + (size_t)rB * 64 + co, o1);
    __syncthreads();
    sh_put2(S, lane, co, o0, o1);
    __syncthreads();

    float t0[16], t1[16];
#pragma unroll
    for (int j = 0; j < 16; ++j) { t0[j] = m1b[co + j]; t1[j] = t0[j]; }
    gemm16x2(S[lane], S[64 + lane], m1w + co, t0, t1, 1.0f, 1.0f);
#pragma unroll
    for (int j = 0; j < 16; ++j) { t0[j] = fmaxf(t0[j], 0.0f); t1[j] = fmaxf(t1[j], 0.0f); }
    __syncthreads();
    sh_put2(S, lane, co, t0, t1);
    __syncthreads();

#pragma unroll
    for (int j = 0; j < 16; ++j) { o0[j] = m2b[co + j]; o1[j] = o0[j]; }
    gemm16x2(S[lane], S[64 + lane], m2w + co, o0, o1, 1.0f, 1.0f);
    if (vA) bf16_put16(msgOut + (size_t)rA * 64 + co, o0, true);
    if (vB) bf16_put16(msgOut + (size_t)rB * 64 + co, o1, true);
}

// ---- gather(msgIn) + update + next-layer msg (ping-pong msgOut) ----
__global__ __launch_bounds__(256, 4) void k_update_msg(float* __restrict__ h,
                                                       const int* __restrict__ start,
                                                       const int* __restrict__ csr,
                                                       const ushort_t* __restrict__ msgIn,
                                                       const float* __restrict__ u1,
                                                       const float* __restrict__ b1,
                                                       const float* __restrict__ u2,
                                                       const float* __restrict__ b2,
                                                       const float* __restrict__ m1w,
                                                       const float* __restrict__ m1b,
                                                       const float* __restrict__ m2w,
                                                       const float* __restrict__ m2b,
                                                       ushort_t* __restrict__ msgOut) {
    __shared__ float S[128][SH_STRIDE];
    const int tid = threadIdx.x;
    const int lane = tid & 63;
    const int wid = tid >> 6;
    const int q = __builtin_amdgcn_readfirstlane(wid);
    const int co = q * 16;
    const int r0 = blockIdx.x * 128;
    const int rA = r0 + lane, rB = r0 + 64 + lane;
    const bool vA = rA < N_NODES, vB = rB < N_NODES;
    const int nrows = min(128, N_NODES - r0);

    gather_to_S(start, csr, msgIn, S, r0, nrows, lane, wid);
    float invA = 0.0f, invB = 0.0f;
    if (vA) invA = 1.0f / fmaxf((float)(start[rA + 1] - start[rA]), 1.0f);
    if (vB) invB = 1.0f / fmaxf((float)(start[rB + 1] - start[rB]), 1.0f);
    __syncthreads();

    // u1 agg part
    float t0[16], t1[16];
#pragma unroll
    for (int j = 0; j < 16; ++j) { t0[j] = b1[co + j]; t1[j] = t0[j]; }
    gemm16x2(S[lane], S[64 + lane], u1 + 64 * 64 + co, t0, t1, invA, invB);
    __syncthreads();
    // u1 h part (+ residual grab)
    stage128(h + (size_t)r0 * 64, S, tid, nrows);
    __syncthreads();
    gemm16x2(S[lane], S[64 + lane], u1 + co, t0, t1, 1.0f, 1.0f);
    float res0[16], res1[16];
#pragma unroll
    for (int j = 0; j < 16; ++j) {
        res0[j] = S[lane][co + j];
        res1[j] = S[64 + lane][co + j];
        t0[j] = fmaxf(t0[j], 0.0f);
        t1[j] = fmaxf(t1[j], 0.0f);
    }
    __syncthreads();
    sh_put2(S, lane, co, t0, t1);
    __syncthreads();

    // u2 + residual -> h_new
    float o0[16], o1[16];
#pragma unroll
    for (int j = 0; j < 16; ++j) { o0[j] = b2[co + j]; o1[j] = o0[j]; }
    gemm16x2(S[lane], S[64 + lane], u2 + co, o0, o1, 1.0f, 1.0f);
#pragma unroll
    for (int j = 0; j < 16; ++j) { o0[j] += res0[j]; o1[j] += res1[j]; }
    if (vA) g_put16(h + (size_t)rA * 64 + co, o0);
    if (vB) g_put16(h + (size_t)rB * 64 + co, o1);
    __syncthreads();
    sh_put2(S, lane, co, o0, o1);
    __syncthreads();

    // m1
#pragma unroll
    for (int j = 0; j < 16; ++j) { t0[j] = m1b[co + j]; t1[j] = t0[j]; }
    gemm16x2(S[lane], S[64 + lane], m1w + co, t0, t1, 1.0f, 1.0f);
#pragma unroll
    for (int j = 0; j < 16; ++j) { t0[j] = fmaxf(t0[j], 0.0f); t1[j] = fmaxf(t1[j], 0.0f); }
    __syncthreads();
    sh_put2(S, lane, co, t0, t1);
    __syncthreads();

    // m2
#pragma unroll
    for (int j = 0; j < 16; ++j) { o0[j] = m2b[co + j]; o1[j] = o0[j]; }
    gemm16x2(S[lane], S[64 + lane], m2w + co, o0, o1, 1.0f, 1.0f);
    if (vA) bf16_put16(msgOut + (size_t)rA * 64 + co, o0, true);
    if (vB) bf16_put16(msgOut + (size_t)rB * 64 + co, o1, true);
}

// ---- gather(msgIn) + update + head precompute ----
__global__ __launch_bounds__(256, 4) void k_update_headpre(const float* __restrict__ h,
                                                           const int* __restrict__ start,
                                                           const int* __restrict__ csr,
                                                           const ushort_t* __restrict__ msgIn,
                                                           const float* __restrict__ u1,
                                                           const float* __restrict__ b1,
                                                           const float* __restrict__ u2,
                                                           const float* __restrict__ b2,
                                                           const float* __restrict__ hw1,
                                                           const float* __restrict__ hb1,
                                                           ushort_t* __restrict__ hA16,
                                                           ushort_t* __restrict__ hB16) {
    __shared__ float S[128][SH_STRIDE];
    const int tid = threadIdx.x;
    const int lane = tid & 63;
    const int wid = tid >> 6;
    const int q = __builtin_amdgcn_readfirstlane(wid);
    const int co = q * 16;
    const int r0 = blockIdx.x * 128;
    const int rA = r0 + lane, rB = r0 + 64 + lane;
    const bool vA = rA < N_NODES, vB = rB < N_NODES;
    const int nrows = min(128, N_NODES - r0);

    gather_to_S(start, csr, msgIn, S, r0, nrows, lane, wid);
    float dvA = 0.0f, dvB = 0.0f;
    if (vA) dvA = (float)(start[rA + 1] - start[rA]);
    if (vB) dvB = (float)(start[rB + 1] - start[rB]);
    float invA = 1.0f / fmaxf(dvA, 1.0f);
    float invB = 1.0f / fmaxf(dvB, 1.0f);
    __syncthreads();

    float t0[16], t1[16];
#pragma unroll
    for (int j = 0; j < 16; ++j) { t0[j] = b1[co + j]; t1[j] = t0[j]; }
    gemm16x2(S[lane], S[64 + lane], u1 + 64 * 64 + co, t0, t1, invA, invB);
    __syncthreads();
    stage128(h + (size_t)r0 * 64, S, tid, nrows);
    __syncthreads();
    gemm16x2(S[lane], S[64 + lane], u1 + co, t0, t1, 1.0f, 1.0f);
    float res0[16], res1[16];
#pragma unroll
    for (int j = 0; j < 16; ++j) {
        res0[j] = S[lane][co + j];
        res1[j] = S[64 + lane][co + j];
        t0[j] = fmaxf(t0[j], 0.0f);
        t1[j] = fmaxf(t1[j], 0.0f);
    }
    __syncthreads();
    sh_put2(S, lane, co, t0, t1);
    __syncthreads();

    float o0[16], o1[16];
#pragma unroll
    for (int j = 0; j < 16; ++j) { o0[j] = b2[co + j]; o1[j] = o0[j]; }
    gemm16x2(S[lane], S[64 + lane], u2 + co, o0, o1, 1.0f, 1.0f);
#pragma unroll
    for (int j = 0; j < 16; ++j) { o0[j] += res0[j]; o1[j] += res1[j]; }
    __syncthreads();
    sh_put2(S, lane, co, o0, o1);     // S = h_new rows
    __syncthreads();

    // headpre A
#pragma unroll
    for (int j = 0; j < 16; ++j) {
        t0[j] = hb1[co + j] + dvA * hw1[128 * 64 + co + j];
        t1[j] = hb1[co + j] + dvB * hw1[128 * 64 + co + j];
    }
    gemm16x2(S[lane], S[64 + lane], hw1 + co, t0, t1, 1.0f, 1.0f);
    if (vA) bf16_put16(hA16 + (size_t)rA * 64 + co, t0, false);
    if (vB) bf16_put16(hA16 + (size_t)rB * 64 + co, t1, false);

    // headpre B (same S contents, no barrier needed)
#pragma unroll
    for (int j = 0; j < 16; ++j) {
        t0[j] = dvA * hw1[129 * 64 + co + j];
        t1[j] = dvB * hw1[129 * 64 + co + j];
    }
    gemm16x2(S[lane], S[64 + lane], hw1 + 64 * 64 + co, t0, t1, 1.0f, 1.0f);
    if (vA) bf16_put16(hB16 + (size_t)rA * 64 + co, t0, false);
    if (vB) bf16_put16(hB16 + (size_t)rB * 64 + co, t1, false);
}

// ------- out[e] = out[e+HALF] = softplus(relu(hA[src]+hB[dst]) . h2w + h2b) + 1e-6 ------
__global__ __launch_bounds__(256) void k_head(const int* __restrict__ rowIdx,
                                              const int* __restrict__ colIdx,
                                              const ushort_t* __restrict__ hA16,
                                              const ushort_t* __restrict__ hB16,
                                              const float* __restrict__ w2,
                                              const float* __restrict__ b2,
                                              float* __restrict__ out) {
    const int lane = threadIdx.x & 63;
    const int sub = lane & 15;
    const int grp = lane >> 4;
    const int waveId = (blockIdx.x * 256 + threadIdx.x) >> 6;
    const int step = gridDim.x * 4 * 4;
    const float4 wv = *(const float4*)(w2 + sub * 4);
    const float b2v = b2[0];
    for (int e = waveId * 4 + grp; e < HALF_E; e += step) {
        int s = rowIdx[e];
        int d = colIdx[e];
        ushort4 a4 = *(const ushort4*)(hA16 + (size_t)s * 64 + sub * 4);
        ushort4 b4 = *(const ushort4*)(hB16 + (size_t)d * 64 + sub * 4);
        float t0 = fmaxf(bf16_f(a4.x) + bf16_f(b4.x), 0.0f);
        float t1 = fmaxf(bf16_f(a4.y) + bf16_f(b4.y), 0.0f);
        float t2 = fmaxf(bf16_f(a4.z) + bf16_f(b4.z), 0.0f);
        float t3 = fmaxf(bf16_f(a4.w) + bf16_f(b4.w), 0.0f);
        float p = t0 * wv.x + t1 * wv.y + t2 * wv.z + t3 * wv.w;
        p += __shfl_xor(p, 1);
        p += __shfl_xor(p, 2);
        p += __shfl_xor(p, 4);
        p += __shfl_xor(p, 8);
        if (sub == 0) {
            float sv = p + b2v;
            float sp = fmaxf(sv, 0.0f) + log1pf(expf(-fabsf(sv)));
            float wvv = sp + 1e-6f;
            out[e] = wvv;
            out[e + HALF_E] = wvv;
        }
    }
}

extern "C" void kernel_launch(void* const* d_in, const int* in_sizes, int n_in,
                              void* d_out, int out_size, void* d_ws, size_t ws_size,
                              hipStream_t stream) {
    const float* x      = (const float*)d_in[0];
    const int*   rowIdx = (const int*)d_in[1];
    const int*   colIdx = rowIdx + E_EDGES;
    const float* w_in   = (const float*)d_in[2];
    const float* b_in   = (const float*)d_in[3];
    const float* l0_m1w = (const float*)d_in[4];
    const float* l0_m1b = (const float*)d_in[5];
    const float* l0_m2w = (const float*)d_in[6];
    const float* l0_m2b = (const float*)d_in[7];
    const float* l0_u1w = (const float*)d_in[8];
    const float* l0_u1b = (const float*)d_in[9];
    const float* l0_u2w = (const float*)d_in[10];
    const float* l0_u2b = (const float*)d_in[11];
    const float* l1_m1w = (const float*)d_in[12];
    const float* l1_m1b = (const float*)d_in[13];
    const float* l1_m2w = (const float*)d_in[14];
    const float* l1_m2b = (const float*)d_in[15];
    const float* l1_u1w = (const float*)d_in[16];
    const float* l1_u1b = (const float*)d_in[17];
    const float* l1_u2w = (const float*)d_in[18];
    const float* l1_u2b = (const float*)d_in[19];
    const float* h1w    = (const float*)d_in[20];
    const float* h1b    = (const float*)d_in[21];
    const float* h2w    = (const float*)d_in[22];
    const float* h2b    = (const float*)d_in[23];

    float* out = (float*)d_out;

    float*    h     = (float*)d_ws;                         // N x 64 f32
    ushort_t* msgA  = (ushort_t*)(h + (size_t)N_NODES * 64); // N x 64 bf16 (msg0; later hA16)
    ushort_t* msgB  = msgA + (size_t)N_NODES * 64;          // N x 64 bf16 (msg1)
    ushort_t* hB16  = msgB + (size_t)N_NODES * 64;          // N x 64 bf16
    int*      start = (int*)(hB16 + (size_t)N_NODES * 64);  // N + 1
    int*      bcnt  = start + N_NODES + 1;                  // 256
    int*      bbase = bcnt + NBUCK;                         // 257 (pad 32)
    int*      curA  = bbase + NBUCK + 32;                   // 256
    int*      csr   = curA + NBUCK;                         // E
    uint2*    pairs = (uint2*)h;                            // alias: h written after CSR done
    ushort_t* hA16  = msgA;                                 // alias: msgA dead after gather0

    const int nb128 = (N_NODES + 127) / 128;                // 782 blocks for MLP kernels

    // ---- CSR build ----
    hipMemsetAsync(bcnt, 0, NBUCK * sizeof(int), stream);
    k_bhist<<<2048, 256, 0, stream>>>(rowIdx, bcnt);
    k_bscan256<<<1, 256, 0, stream>>>(bcnt, bbase, curA, start);
    k_bucketA<<<NBLK_A, 256, 0, stream>>>(rowIdx, colIdx, curA, pairs);
    k_bucketB<<<NBUCK, 256, 0, stream>>>(bbase, pairs, start, csr);

    // ---- input linear + layer0 message ----
    k_lin_msg<<<nb128, 256, 0, stream>>>(x, w_in, b_in,
                                         l0_m1w, l0_m1b, l0_m2w, l0_m2b, h, msgA);
    // ---- layer0: gather(msgA) + update + layer1 message -> msgB ----
    k_update_msg<<<nb128, 256, 0, stream>>>(h, start, csr, msgA,
                                            l0_u1w, l0_u1b, l0_u2w, l0_u2b,
                                            l1_m1w, l1_m1b, l1_m2w, l1_m2b, msgB);
    // ---- layer1: gather(msgB) + update + head precompute ----
    k_update_headpre<<<nb128, 256, 0, stream>>>(h, start, csr, msgB,
                                                l1_u1w, l1_u1b, l1_u2w, l1_u2b,
                                                h1w, h1b, hA16, hB16);
    // ---- head ----
    k_head<<<4096, 256, 0, stream>>>(rowIdx, colIdx, hA16, hB16, h2w, h2b, out);
}

// Round 11
// 429.176 us; speedup vs baseline: 1.1595x; 1.1595x over previous
//
#include <hip/hip_runtime.h>
#include <math.h>

#define N_NODES 100000
#define E_EDGES 1600000
#define HALF_E  (E_EDGES / 2)

#define NBUCK 256
#define ROWS_PER_BUCKET ((N_NODES + NBUCK - 1) / NBUCK)   // 391
#define EDGES_PER_BLK_A 4096
#define NBLK_A ((E_EDGES + EDGES_PER_BLK_A - 1) / EDGES_PER_BLK_A)  // 391

typedef unsigned short ushort_t;

// ---- bf16 helpers (RNE pack, cheap unpack) ----
__device__ __forceinline__ unsigned bf16_1(float f) {
    unsigned u = __float_as_uint(f);
    return (u + 0x7fffu + ((u >> 16) & 1u)) >> 16;
}
__device__ __forceinline__ unsigned bf16_2(float a, float b) {
    return bf16_1(a) | (bf16_1(b) << 16);
}
__device__ __forceinline__ float bf16_f(ushort_t us) {
    return __uint_as_float(((unsigned)us) << 16);
}

// ============ CSR build (bucketed) ============

__global__ __launch_bounds__(256) void k_bhist(const int* __restrict__ rowIdx,
                                               int* __restrict__ bcnt) {
    __shared__ int c[NBUCK];
    const int tid = threadIdx.x;
    c[tid] = 0;
    __syncthreads();
    for (int e = blockIdx.x * 256 + tid; e < E_EDGES; e += gridDim.x * 256)
        atomicAdd(&c[rowIdx[e] / ROWS_PER_BUCKET], 1);
    __syncthreads();
    if (c[tid]) atomicAdd(&bcnt[tid], c[tid]);
}

__global__ __launch_bounds__(256) void k_bscan256(const int* __restrict__ bcnt,
                                                  int* __restrict__ bbase,
                                                  int* __restrict__ curA,
                                                  int* __restrict__ start) {
    __shared__ int sc[NBUCK];
    const int tid = threadIdx.x;
    int v = bcnt[tid];
    sc[tid] = v;
    __syncthreads();
    for (int st = 1; st < 256; st <<= 1) {
        int t = (tid >= st) ? sc[tid - st] : 0;
        __syncthreads();
        sc[tid] += t;
        __syncthreads();
    }
    int excl = sc[tid] - v;
    bbase[tid] = excl;
    curA[tid] = excl;
    if (tid == 255) bbase[256] = sc[255];
    if (tid == 0) start[N_NODES] = E_EDGES;
}

__global__ __launch_bounds__(256) void k_bucketA(const int* __restrict__ rowIdx,
                                                 const int* __restrict__ colIdx,
                                                 int* __restrict__ cursorA,
                                                 uint2* __restrict__ pairs) {
    __shared__ uint2 stage[EDGES_PER_BLK_A];
    __shared__ unsigned char bmap[EDGES_PER_BLK_A];
    __shared__ int cntL[NBUCK], scanEx[NBUCK], cur[NBUCK], posG[NBUCK];
    const int tid = threadIdx.x;
    const int e0 = blockIdx.x * EDGES_PER_BLK_A;
    const int n = min(EDGES_PER_BLK_A, E_EDGES - e0);

    cntL[tid] = 0;
    __syncthreads();
    for (int i = tid; i < n; i += 256) {
        int b = rowIdx[e0 + i] / ROWS_PER_BUCKET;
        atomicAdd(&cntL[b], 1);
    }
    __syncthreads();
    int myc = cntL[tid];
    scanEx[tid] = myc;
    __syncthreads();
    for (int st = 1; st < 256; st <<= 1) {
        int t = (tid >= st) ? scanEx[tid - st] : 0;
        __syncthreads();
        scanEx[tid] += t;
        __syncthreads();
    }
    int ex = scanEx[tid] - myc;
    __syncthreads();
    scanEx[tid] = ex;
    cur[tid] = ex;
    if (myc) posG[tid] = atomicAdd(&cursorA[tid], myc);
    __syncthreads();
    for (int i = tid; i < n; i += 256) {
        int r = rowIdx[e0 + i];
        int c = colIdx[e0 + i];
        int b = r / ROWS_PER_BUCKET;
        int slot = atomicAdd(&cur[b], 1);
        stage[slot] = make_uint2((unsigned)c, (unsigned)r);
        bmap[slot] = (unsigned char)b;
    }
    __syncthreads();
    for (int i = tid; i < n; i += 256) {
        int b = bmap[i];
        int dst = posG[b] + (i - scanEx[b]);
        pairs[dst] = stage[i];
    }
}

__global__ __launch_bounds__(256) void k_bucketB(const int* __restrict__ bbase,
                                                 const uint2* __restrict__ pairs,
                                                 int* __restrict__ start,
                                                 int* __restrict__ csr) {
    __shared__ int cur[ROWS_PER_BUCKET];
    __shared__ int scn[512];
    const int tid = threadIdx.x;
    const int rowbase = blockIdx.x * ROWS_PER_BUCKET;
    const int nrows = min(ROWS_PER_BUCKET, N_NODES - rowbase);
    for (int i = tid; i < nrows; i += 256) cur[i] = 0;
    __syncthreads();
    const int bBeg = bbase[blockIdx.x];
    const int bEnd = bbase[blockIdx.x + 1];
    for (int i = bBeg + tid; i < bEnd; i += 256)
        atomicAdd(&cur[(int)pairs[i].y - rowbase], 1);
    __syncthreads();
    scn[tid] = (tid < nrows) ? cur[tid] : 0;
    scn[tid + 256] = (tid + 256 < nrows) ? cur[tid + 256] : 0;
    __syncthreads();
    for (int st = 1; st < 512; st <<= 1) {
        int i0 = tid, i1 = tid + 256;
        int t0 = (i0 >= st) ? scn[i0 - st] : 0;
        int t1 = (i1 >= st) ? scn[i1 - st] : 0;
        __syncthreads();
        scn[i0] += t0;
        scn[i1] += t1;
        __syncthreads();
    }
    for (int i = tid; i < nrows; i += 256) {
        int sv = bBeg + scn[i] - cur[i];
        start[rowbase + i] = sv;
        cur[i] = sv;
    }
    __syncthreads();
    for (int i = bBeg + tid; i < bEnd; i += 256) {
        uint2 p = pairs[i];
        int pos = atomicAdd(&cur[(int)p.y - rowbase], 1);
        csr[pos] = (int)p.x;
    }
}

// ============ fused node MLPs (R9 structure: proven best) ============
// Block = 256 thr = 4 waves; 64 rows/block; row = lane, column-quarter = wave id
// (wave-uniform weight columns => s_load/SGPR weights). ONE f32 LDS buffer
// [64][68] (17.4 KB).

#define SH_STRIDE 68

__device__ __forceinline__ void gemm16(const float* xrow,
                                       const float* __restrict__ wc,
                                       float o[16], float scale) {
#pragma unroll 4
    for (int k = 0; k < 64; ++k) {
        float xk = xrow[k] * scale;
        const float* wr = wc + k * 64;
#pragma unroll
        for (int j = 0; j < 16; ++j) o[j] = fmaf(xk, wr[j], o[j]);
    }
}

__device__ __forceinline__ void stage64(const float* __restrict__ src,
                                        float S[64][SH_STRIDE], int tid, int nrows) {
#pragma unroll
    for (int i = 0; i < 4; ++i) {
        int idx = tid + i * 256;
        int row = idx >> 4;
        int c4 = (idx & 15) * 4;
        float4 v = (row < nrows) ? *(const float4*)(src + (size_t)row * 64 + c4)
                                 : make_float4(0.f, 0.f, 0.f, 0.f);
        *(float4*)(&S[row][c4]) = v;
    }
}

__device__ __forceinline__ void stageX(const float* __restrict__ xbase,
                                       float S[64][SH_STRIDE], int tid, int nrows) {
#pragma unroll
    for (int i = 0; i < 4; ++i) {
        int idx = tid + i * 256;
        int row = idx >> 4;
        int c4 = (idx & 15) * 4;
        float4 v = (row < nrows) ? *(const float4*)(xbase + (size_t)row * 128 + c4)
                                 : make_float4(0.f, 0.f, 0.f, 0.f);
        *(float4*)(&S[row][c4]) = v;
    }
}

__device__ __forceinline__ void sh_put16(float S[64][SH_STRIDE], int lane, int co,
                                         const float o[16]) {
    *(float4*)(&S[lane][co + 0])  = make_float4(o[0], o[1], o[2], o[3]);
    *(float4*)(&S[lane][co + 4])  = make_float4(o[4], o[5], o[6], o[7]);
    *(float4*)(&S[lane][co + 8])  = make_float4(o[8], o[9], o[10], o[11]);
    *(float4*)(&S[lane][co + 12]) = make_float4(o[12], o[13], o[14], o[15]);
}

__device__ __forceinline__ void g_put16(float* __restrict__ dst, const float o[16]) {
    *(float4*)(dst + 0)  = make_float4(o[0], o[1], o[2], o[3]);
    *(float4*)(dst + 4)  = make_float4(o[4], o[5], o[6], o[7]);
    *(float4*)(dst + 8)  = make_float4(o[8], o[9], o[10], o[11]);
    *(float4*)(dst + 12) = make_float4(o[12], o[13], o[14], o[15]);
}

__device__ __forceinline__ void bf16_put16(ushort_t* __restrict__ dst, const float o[16],
                                           bool relu) {
    float a[16];
#pragma unroll
    for (int j = 0; j < 16; ++j) a[j] = relu ? fmaxf(o[j], 0.0f) : o[j];
    uint4* mv = (uint4*)dst;
    mv[0] = make_uint4(bf16_2(a[0], a[1]), bf16_2(a[2], a[3]),
                       bf16_2(a[4], a[5]), bf16_2(a[6], a[7]));
    mv[1] = make_uint4(bf16_2(a[8], a[9]), bf16_2(a[10], a[11]),
                       bf16_2(a[12], a[13]), bf16_2(a[14], a[15]));
}

// h = x@w_in+b_in ; msg16 = relu(relu(h@m1+b1)@m2+b2)
__global__ __launch_bounds__(256, 4) void k_lin_msg(const float* __restrict__ x,
                                                    const float* __restrict__ w,
                                                    const float* __restrict__ b,
                                                    const float* __restrict__ m1w,
                                                    const float* __restrict__ m1b,
                                                    const float* __restrict__ m2w,
                                                    const float* __restrict__ m2b,
                                                    float* __restrict__ h,
                                                    ushort_t* __restrict__ msg16) {
    __shared__ float S[64][SH_STRIDE];
    const int tid = threadIdx.x;
    const int lane = tid & 63;
    const int q = __builtin_amdgcn_readfirstlane(tid >> 6);
    const int co = q * 16;
    const int r0 = blockIdx.x * 64;
    const int r = r0 + lane;
    const bool valid = r < N_NODES;
    const int nrows = min(64, N_NODES - r0);

    float o[16];
#pragma unroll
    for (int j = 0; j < 16; ++j) o[j] = b[co + j];
    stageX(x + (size_t)r0 * 128, S, tid, nrows);
    __syncthreads();
    gemm16(S[lane], w + co, o, 1.0f);
    __syncthreads();
    stageX(x + (size_t)r0 * 128 + 64, S, tid, nrows);
    __syncthreads();
    gemm16(S[lane], w + 64 * 64 + co, o, 1.0f);
    if (valid) g_put16(h + (size_t)r * 64 + co, o);
    __syncthreads();
    sh_put16(S, lane, co, o);
    __syncthreads();

    float t[16];
#pragma unroll
    for (int j = 0; j < 16; ++j) t[j] = m1b[co + j];
    gemm16(S[lane], m1w + co, t, 1.0f);
#pragma unroll
    for (int j = 0; j < 16; ++j) t[j] = fmaxf(t[j], 0.0f);
    __syncthreads();
    sh_put16(S, lane, co, t);
    __syncthreads();

#pragma unroll
    for (int j = 0; j < 16; ++j) o[j] = m2b[co + j];
    gemm16(S[lane], m2w + co, o, 1.0f);
    if (valid) bf16_put16(msg16 + (size_t)r * 64 + co, o, true);
}

// ============ aggregation: gather, 4 edges per VMEM instruction ============
// lane = (edge-of-quad q4 = lane>>4, row-slice s16 = lane&15). Each lane loads
// ushort4 (8B) -> 512B per wave instruction; 4x fewer VMEM + bpermute than
// the 1-edge/instr version. Final shfl_xor(16/32) folds the 4 edge quads.
__global__ __launch_bounds__(256) void k_gather(const int* __restrict__ start,
                                                const int* __restrict__ csr,
                                                const ushort_t* __restrict__ msg16,
                                                float* __restrict__ agg) {
    const int lane = threadIdx.x & 63;
    const int wid  = threadIdx.x >> 6;
    const int q4   = lane >> 4;
    const int s16  = lane & 15;
    int r = blockIdx.x * 4 + wid;
    if (r >= N_NODES) return;
    int b = start[r];
    int e0 = start[r + 1];
    float a0 = 0.f, a1 = 0.f, a2 = 0.f, a3 = 0.f;
    for (int base = b; base < e0; base += 64) {
        int n = e0 - base;
        if (n > 64) n = 64;
        int c = 0;
        if (base + lane < e0) c = csr[base + lane];
#pragma unroll 2
        for (int j = 0; j < n; j += 4) {
            int jj = j + q4;
            bool act = jj < n;
            int cj = __shfl(c, act ? jj : 0, 64);
            ushort4 v = *(const ushort4*)(msg16 + (size_t)cj * 64 + s16 * 4);
            if (act) {
                a0 += bf16_f(v.x);
                a1 += bf16_f(v.y);
                a2 += bf16_f(v.z);
                a3 += bf16_f(v.w);
            }
        }
    }
    a0 += __shfl_xor(a0, 16, 64); a0 += __shfl_xor(a0, 32, 64);
    a1 += __shfl_xor(a1, 16, 64); a1 += __shfl_xor(a1, 32, 64);
    a2 += __shfl_xor(a2, 16, 64); a2 += __shfl_xor(a2, 32, 64);
    a3 += __shfl_xor(a3, 16, 64); a3 += __shfl_xor(a3, 32, 64);
    if (q4 == 0)
        *(float4*)(agg + (size_t)r * 64 + s16 * 4) = make_float4(a0, a1, a2, a3);
}

// ---- update layer0 then msg layer1, fused (single LDS buffer) ----
__global__ __launch_bounds__(256, 4) void k_update_msg(float* __restrict__ h,
                                                       const float* __restrict__ agg,
                                                       const int* __restrict__ start,
                                                       const float* __restrict__ u1,
                                                       const float* __restrict__ b1,
                                                       const float* __restrict__ u2,
                                                       const float* __restrict__ b2,
                                                       const float* __restrict__ m1w,
                                                       const float* __restrict__ m1b,
                                                       const float* __restrict__ m2w,
                                                       const float* __restrict__ m2b,
                                                       ushort_t* __restrict__ msg16) {
    __shared__ float S[64][SH_STRIDE];
    const int tid = threadIdx.x;
    const int lane = tid & 63;
    const int q = __builtin_amdgcn_readfirstlane(tid >> 6);
    const int co = q * 16;
    const int r0 = blockIdx.x * 64;
    const int r = r0 + lane;
    const bool valid = r < N_NODES;
    const int nrows = min(64, N_NODES - r0);

    float inv = 0.0f;
    if (valid) {
        float dv = (float)(start[r + 1] - start[r]);
        inv = 1.0f / fmaxf(dv, 1.0f);
    }

    float t[16];
#pragma unroll
    for (int j = 0; j < 16; ++j) t[j] = b1[co + j];
    stage64(agg + (size_t)r0 * 64, S, tid, nrows);
    __syncthreads();
    gemm16(S[lane], u1 + 64 * 64 + co, t, inv);
    __syncthreads();
    stage64(h + (size_t)r0 * 64, S, tid, nrows);
    __syncthreads();
    gemm16(S[lane], u1 + co, t, 1.0f);
    float res[16];
#pragma unroll
    for (int j = 0; j < 16; ++j) {
        res[j] = S[lane][co + j];
        t[j] = fmaxf(t[j], 0.0f);
    }
    __syncthreads();
    sh_put16(S, lane, co, t);
    __syncthreads();

    float o[16];
#pragma unroll
    for (int j = 0; j < 16; ++j) o[j] = b2[co + j];
    gemm16(S[lane], u2 + co, o, 1.0f);
#pragma unroll
    for (int j = 0; j < 16; ++j) o[j] += res[j];
    if (valid) g_put16(h + (size_t)r * 64 + co, o);
    __syncthreads();
    sh_put16(S, lane, co, o);
    __syncthreads();

#pragma unroll
    for (int j = 0; j < 16; ++j) t[j] = m1b[co + j];
    gemm16(S[lane], m1w + co, t, 1.0f);
#pragma unroll
    for (int j = 0; j < 16; ++j) t[j] = fmaxf(t[j], 0.0f);
    __syncthreads();
    sh_put16(S, lane, co, t);
    __syncthreads();

#pragma unroll
    for (int j = 0; j < 16; ++j) o[j] = m2b[co + j];
    gemm16(S[lane], m2w + co, o, 1.0f);
    if (valid) bf16_put16(msg16 + (size_t)r * 64 + co, o, true);
}

// ---- update layer1 then head precompute, fused (single LDS buffer) ----
__global__ __launch_bounds__(256, 4) void k_update_headpre(const float* __restrict__ h,
                                                           const float* __restrict__ agg,
                                                           const int* __restrict__ start,
                                                           const float* __restrict__ u1,
                                                           const float* __restrict__ b1,
                                                           const float* __restrict__ u2,
                                                           const float* __restrict__ b2,
                                                           const float* __restrict__ hw1,
                                                           const float* __restrict__ hb1,
                                                           ushort_t* __restrict__ hA16,
                                                           ushort_t* __restrict__ hB16) {
    __shared__ float S[64][SH_STRIDE];
    const int tid = threadIdx.x;
    const int lane = tid & 63;
    const int q = __builtin_amdgcn_readfirstlane(tid >> 6);
    const int co = q * 16;
    const int r0 = blockIdx.x * 64;
    const int r = r0 + lane;
    const bool valid = r < N_NODES;
    const int nrows = min(64, N_NODES - r0);

    float dv = 0.0f;
    if (valid) dv = (float)(start[r + 1] - start[r]);
    float inv = 1.0f / fmaxf(dv, 1.0f);

    float t[16];
#pragma unroll
    for (int j = 0; j < 16; ++j) t[j] = b1[co + j];
    stage64(agg + (size_t)r0 * 64, S, tid, nrows);
    __syncthreads();
    gemm16(S[lane], u1 + 64 * 64 + co, t, inv);
    __syncthreads();
    stage64(h + (size_t)r0 * 64, S, tid, nrows);
    __syncthreads();
    gemm16(S[lane], u1 + co, t, 1.0f);
    float res[16];
#pragma unroll
    for (int j = 0; j < 16; ++j) {
        res[j] = S[lane][co + j];
        t[j] = fmaxf(t[j], 0.0f);
    }
    __syncthreads();
    sh_put16(S, lane, co, t);
    __syncthreads();

    float o[16];
#pragma unroll
    for (int j = 0; j < 16; ++j) o[j] = b2[co + j];
    gemm16(S[lane], u2 + co, o, 1.0f);
#pragma unroll
    for (int j = 0; j < 16; ++j) o[j] += res[j];
    __syncthreads();
    sh_put16(S, lane, co, o);     // S = h_new rows
    __syncthreads();

    // headpre A
#pragma unroll
    for (int j = 0; j < 16; ++j) t[j] = hb1[co + j] + dv * hw1[128 * 64 + co + j];
    gemm16(S[lane], hw1 + co, t, 1.0f);
    if (valid) bf16_put16(hA16 + (size_t)r * 64 + co, t, false);

    // headpre B (same S, no barrier needed)
#pragma unroll
    for (int j = 0; j < 16; ++j) t[j] = dv * hw1[129 * 64 + co + j];
    gemm16(S[lane], hw1 + 64 * 64 + co, t, 1.0f);
    if (valid) bf16_put16(hB16 + (size_t)r * 64 + co, t, false);
}

// ------- out[e] = out[e+HALF] = softplus(relu(hA[src]+hB[dst]) . h2w + h2b) + 1e-6 ------
__global__ __launch_bounds__(256) void k_head(const int* __restrict__ rowIdx,
                                              const int* __restrict__ colIdx,
                                              const ushort_t* __restrict__ hA16,
                                              const ushort_t* __restrict__ hB16,
                                              const float* __restrict__ w2,
                                              const float* __restrict__ b2,
                                              float* __restrict__ out) {
    const int lane = threadIdx.x & 63;
    const int sub = lane & 15;
    const int grp = lane >> 4;
    const int waveId = (blockIdx.x * 256 + threadIdx.x) >> 6;
    const int step = gridDim.x * 4 * 4;
    const float4 wv = *(const float4*)(w2 + sub * 4);
    const float b2v = b2[0];
    for (int e = waveId * 4 + grp; e < HALF_E; e += step) {
        int s = rowIdx[e];
        int d = colIdx[e];
        ushort4 a4 = *(const ushort4*)(hA16 + (size_t)s * 64 + sub * 4);
        ushort4 b4 = *(const ushort4*)(hB16 + (size_t)d * 64 + sub * 4);
        float t0 = fmaxf(bf16_f(a4.x) + bf16_f(b4.x), 0.0f);
        float t1 = fmaxf(bf16_f(a4.y) + bf16_f(b4.y), 0.0f);
        float t2 = fmaxf(bf16_f(a4.z) + bf16_f(b4.z), 0.0f);
        float t3 = fmaxf(bf16_f(a4.w) + bf16_f(b4.w), 0.0f);
        float p = t0 * wv.x + t1 * wv.y + t2 * wv.z + t3 * wv.w;
        p += __shfl_xor(p, 1);
        p += __shfl_xor(p, 2);
        p += __shfl_xor(p, 4);
        p += __shfl_xor(p, 8);
        if (sub == 0) {
            float sv = p + b2v;
            float sp = fmaxf(sv, 0.0f) + log1pf(expf(-fabsf(sv)));
            float wvv = sp + 1e-6f;
            out[e] = wvv;
            out[e + HALF_E] = wvv;
        }
    }
}

extern "C" void kernel_launch(void* const* d_in, const int* in_sizes, int n_in,
                              void* d_out, int out_size, void* d_ws, size_t ws_size,
                              hipStream_t stream) {
    const float* x      = (const float*)d_in[0];
    const int*   rowIdx = (const int*)d_in[1];
    const int*   colIdx = rowIdx + E_EDGES;
    const float* w_in   = (const float*)d_in[2];
    const float* b_in   = (const float*)d_in[3];
    const float* l0_m1w = (const float*)d_in[4];
    const float* l0_m1b = (const float*)d_in[5];
    const float* l0_m2w = (const float*)d_in[6];
    const float* l0_m2b = (const float*)d_in[7];
    const float* l0_u1w = (const float*)d_in[8];
    const float* l0_u1b = (const float*)d_in[9];
    const float* l0_u2w = (const float*)d_in[10];
    const float* l0_u2b = (const float*)d_in[11];
    const float* l1_m1w = (const float*)d_in[12];
    const float* l1_m1b = (const float*)d_in[13];
    const float* l1_m2w = (const float*)d_in[14];
    const float* l1_m2b = (const float*)d_in[15];
    const float* l1_u1w = (const float*)d_in[16];
    const float* l1_u1b = (const float*)d_in[17];
    const float* l1_u2w = (const float*)d_in[18];
    const float* l1_u2b = (const float*)d_in[19];
    const float* h1w    = (const float*)d_in[20];
    const float* h1b    = (const float*)d_in[21];
    const float* h2w    = (const float*)d_in[22];
    const float* h2b    = (const float*)d_in[23];

    float* out = (float*)d_out;

    float*    h     = (float*)d_ws;                         // N x 64 f32
    float*    agg   = h + (size_t)N_NODES * 64;             // N x 64 f32
    ushort_t* msg16 = (ushort_t*)(agg + (size_t)N_NODES * 64); // N x 64 bf16
    ushort_t* hB16  = msg16 + (size_t)N_NODES * 64;         // N x 64 bf16
    int*      start = (int*)(hB16 + (size_t)N_NODES * 64);  // N + 1
    int*      bcnt  = start + N_NODES + 1;                  // 256
    int*      bbase = bcnt + NBUCK;                         // 257 (pad 32)
    int*      curA  = bbase + NBUCK + 32;                   // 256
    int*      csr   = curA + NBUCK;                         // E
    uint2*    pairs = (uint2*)agg;                          // alias: dead before gather writes agg
    ushort_t* hA16  = msg16;                                // alias: msg16 dead after gather1

    const int nb64 = (N_NODES + 63) / 64;                   // 1563 blocks for MLP kernels
    const int gatherBlocks = (N_NODES + 3) / 4;

    // ---- CSR build ----
    hipMemsetAsync(bcnt, 0, NBUCK * sizeof(int), stream);
    k_bhist<<<2048, 256, 0, stream>>>(rowIdx, bcnt);
    k_bscan256<<<1, 256, 0, stream>>>(bcnt, bbase, curA, start);
    k_bucketA<<<NBLK_A, 256, 0, stream>>>(rowIdx, colIdx, curA, pairs);
    k_bucketB<<<NBUCK, 256, 0, stream>>>(bbase, pairs, start, csr);

    // ---- input linear + layer0 message (fused) ----
    k_lin_msg<<<nb64, 256, 0, stream>>>(x, w_in, b_in,
                                        l0_m1w, l0_m1b, l0_m2w, l0_m2b, h, msg16);
    // ---- layer 0 aggregate; update + layer1 message (fused) ----
    k_gather<<<gatherBlocks, 256, 0, stream>>>(start, csr, msg16, agg);
    k_update_msg<<<nb64, 256, 0, stream>>>(h, agg, start,
                                           l0_u1w, l0_u1b, l0_u2w, l0_u2b,
                                           l1_m1w, l1_m1b, l1_m2w, l1_m2b, msg16);
    // ---- layer 1 aggregate; update + head precompute (fused) ----
    k_gather<<<gatherBlocks, 256, 0, stream>>>(start, csr, msg16, agg);
    k_update_headpre<<<nb64, 256, 0, stream>>>(h, agg, start,
                                               l1_u1w, l1_u1b, l1_u2w, l1_u2b,
                                               h1w, h1b, hA16, hB16);
    // ---- head ----
    k_head<<<4096, 256, 0, stream>>>(rowIdx, colIdx, hA16, hB16, h2w, h2b, out);
}

// Round 12
// 330.449 us; speedup vs baseline: 1.5060x; 1.2988x over previous
//
#include <hip/hip_runtime.h>
#include <math.h>

#define N_NODES 100000
#define E_EDGES 1600000
#define HALF_E  (E_EDGES / 2)

#define NBUCK 256
#define ROWS_PER_BUCKET ((N_NODES + NBUCK - 1) / NBUCK)   // 391
#define EDGES_PER_BLK_A 4096
#define NBLK_A ((E_EDGES + EDGES_PER_BLK_A - 1) / EDGES_PER_BLK_A)  // 391

typedef unsigned short ushort_t;
typedef __attribute__((ext_vector_type(8))) short bf16x8;
typedef __attribute__((ext_vector_type(8))) unsigned short u16x8;
typedef __attribute__((ext_vector_type(4))) float f32x4;

#define MFMA16(a, b, c) __builtin_amdgcn_mfma_f32_16x16x32_bf16(a, b, c, 0, 0, 0)

// ---- bf16 helpers (RNE pack, cheap unpack) ----
__device__ __forceinline__ unsigned bf16_1(float f) {
    unsigned u = __float_as_uint(f);
    return (u + 0x7fffu + ((u >> 16) & 1u)) >> 16;
}
__device__ __forceinline__ float bf16_f(ushort_t us) {
    return __uint_as_float(((unsigned)us) << 16);
}

// ============ CSR build (bucketed) ============

__global__ __launch_bounds__(256) void k_bhist(const int* __restrict__ rowIdx,
                                               int* __restrict__ bcnt) {
    __shared__ int c[NBUCK];
    const int tid = threadIdx.x;
    c[tid] = 0;
    __syncthreads();
    for (int e = blockIdx.x * 256 + tid; e < E_EDGES; e += gridDim.x * 256)
        atomicAdd(&c[rowIdx[e] / ROWS_PER_BUCKET], 1);
    __syncthreads();
    if (c[tid]) atomicAdd(&bcnt[tid], c[tid]);
}

__global__ __launch_bounds__(256) void k_bscan256(const int* __restrict__ bcnt,
                                                  int* __restrict__ bbase,
                                                  int* __restrict__ curA,
                                                  int* __restrict__ start) {
    __shared__ int sc[NBUCK];
    const int tid = threadIdx.x;
    int v = bcnt[tid];
    sc[tid] = v;
    __syncthreads();
    for (int st = 1; st < 256; st <<= 1) {
        int t = (tid >= st) ? sc[tid - st] : 0;
        __syncthreads();
        sc[tid] += t;
        __syncthreads();
    }
    int excl = sc[tid] - v;
    bbase[tid] = excl;
    curA[tid] = excl;
    if (tid == 255) bbase[256] = sc[255];
    if (tid == 0) start[N_NODES] = E_EDGES;
}

__global__ __launch_bounds__(256) void k_bucketA(const int* __restrict__ rowIdx,
                                                 const int* __restrict__ colIdx,
                                                 int* __restrict__ cursorA,
                                                 uint2* __restrict__ pairs) {
    __shared__ uint2 stage[EDGES_PER_BLK_A];
    __shared__ unsigned char bmap[EDGES_PER_BLK_A];
    __shared__ int cntL[NBUCK], scanEx[NBUCK], cur[NBUCK], posG[NBUCK];
    const int tid = threadIdx.x;
    const int e0 = blockIdx.x * EDGES_PER_BLK_A;
    const int n = min(EDGES_PER_BLK_A, E_EDGES - e0);

    cntL[tid] = 0;
    __syncthreads();
    for (int i = tid; i < n; i += 256) {
        int b = rowIdx[e0 + i] / ROWS_PER_BUCKET;
        atomicAdd(&cntL[b], 1);
    }
    __syncthreads();
    int myc = cntL[tid];
    scanEx[tid] = myc;
    __syncthreads();
    for (int st = 1; st < 256; st <<= 1) {
        int t = (tid >= st) ? scanEx[tid - st] : 0;
        __syncthreads();
        scanEx[tid] += t;
        __syncthreads();
    }
    int ex = scanEx[tid] - myc;
    __syncthreads();
    scanEx[tid] = ex;
    cur[tid] = ex;
    if (myc) posG[tid] = atomicAdd(&cursorA[tid], myc);
    __syncthreads();
    for (int i = tid; i < n; i += 256) {
        int r = rowIdx[e0 + i];
        int c = colIdx[e0 + i];
        int b = r / ROWS_PER_BUCKET;
        int slot = atomicAdd(&cur[b], 1);
        stage[slot] = make_uint2((unsigned)c, (unsigned)r);
        bmap[slot] = (unsigned char)b;
    }
    __syncthreads();
    for (int i = tid; i < n; i += 256) {
        int b = bmap[i];
        int dst = posG[b] + (i - scanEx[b]);
        pairs[dst] = stage[i];
    }
}

__global__ __launch_bounds__(256) void k_bucketB(const int* __restrict__ bbase,
                                                 const uint2* __restrict__ pairs,
                                                 int* __restrict__ start,
                                                 int* __restrict__ csr) {
    __shared__ int cur[ROWS_PER_BUCKET];
    __shared__ int scn[512];
    const int tid = threadIdx.x;
    const int rowbase = blockIdx.x * ROWS_PER_BUCKET;
    const int nrows = min(ROWS_PER_BUCKET, N_NODES - rowbase);
    for (int i = tid; i < nrows; i += 256) cur[i] = 0;
    __syncthreads();
    const int bBeg = bbase[blockIdx.x];
    const int bEnd = bbase[blockIdx.x + 1];
    for (int i = bBeg + tid; i < bEnd; i += 256)
        atomicAdd(&cur[(int)pairs[i].y - rowbase], 1);
    __syncthreads();
    scn[tid] = (tid < nrows) ? cur[tid] : 0;
    scn[tid + 256] = (tid + 256 < nrows) ? cur[tid + 256] : 0;
    __syncthreads();
    for (int st = 1; st < 512; st <<= 1) {
        int i0 = tid, i1 = tid + 256;
        int t0 = (i0 >= st) ? scn[i0 - st] : 0;
        int t1 = (i1 >= st) ? scn[i1 - st] : 0;
        __syncthreads();
        scn[i0] += t0;
        scn[i1] += t1;
        __syncthreads();
    }
    for (int i = tid; i < nrows; i += 256) {
        int sv = bBeg + scn[i] - cur[i];
        start[rowbase + i] = sv;
        cur[i] = sv;
    }
    __syncthreads();
    for (int i = bBeg + tid; i < bEnd; i += 256) {
        uint2 p = pairs[i];
        int pos = atomicAdd(&cur[(int)p.y - rowbase], 1);
        csr[pos] = (int)p.x;
    }
}

// ============ weight split (fp32 -> fragment-layout bf16 hi/lo) ============
// 14 panels of [64 k x 64 col]. Fragment (h,c,lane): 8 bf16 at
// W[h*32 + (lane>>4)*8 + j][c*16 + (lane&15)], stored contiguous per lane.
__global__ __launch_bounds__(512) void k_wsplit(const float* __restrict__ w_in,
                                                const float* __restrict__ l0_m1w,
                                                const float* __restrict__ l0_m2w,
                                                const float* __restrict__ l0_u1w,
                                                const float* __restrict__ l0_u2w,
                                                const float* __restrict__ l1_m1w,
                                                const float* __restrict__ l1_m2w,
                                                const float* __restrict__ l1_u1w,
                                                const float* __restrict__ l1_u2w,
                                                const float* __restrict__ h1w,
                                                ushort_t* __restrict__ whi,
                                                ushort_t* __restrict__ wlo) {
    const float* src;
    switch (blockIdx.x) {
        case 0:  src = w_in;           break;
        case 1:  src = w_in + 4096;    break;
        case 2:  src = l0_m1w;         break;
        case 3:  src = l0_m2w;         break;
        case 4:  src = l0_u1w;         break;
        case 5:  src = l0_u1w + 4096;  break;
        case 6:  src = l0_u2w;         break;
        case 7:  src = l1_m1w;         break;
        case 8:  src = l1_m2w;         break;
        case 9:  src = l1_u1w;         break;
        case 10: src = l1_u1w + 4096;  break;
        case 11: src = l1_u2w;         break;
        case 12: src = h1w;            break;
        default: src = h1w + 4096;     break;
    }
    const int tid = threadIdx.x;
    const int h = tid >> 8;
    const int c = (tid >> 6) & 3;
    const int lane = tid & 63;
    const int kg = lane >> 4, lr = lane & 15;
    const int col = c * 16 + lr;
    u16x8 hi8, lo8;
#pragma unroll
    for (int j = 0; j < 8; ++j) {
        int k = h * 32 + kg * 8 + j;
        float v = src[k * 64 + col];
        unsigned uh = bf16_1(v);
        hi8[j] = (unsigned short)uh;
        lo8[j] = (unsigned short)bf16_1(v - __uint_as_float(uh << 16));
    }
    size_t idx = (size_t)blockIdx.x * 4096 + ((size_t)(h * 4 + c) * 64 + lane) * 8;
    *(u16x8*)(whi + idx) = hi8;
    *(u16x8*)(wlo + idx) = lo8;
}

// ============ MFMA node-MLP machinery ============
// Block 256 = 4 waves, 64 rows x 64 cols per GEMM. Wave q owns col-tile q.
// Activations in LDS as split bf16: S[64][72] ushort (hi and lo arrays).
// out = act @ W via bf16x3: hi*hi + hi*lo + lo*hi (error ~2^-18).

__device__ __forceinline__ void mfma_gemm64(const ushort_t* Shi, const ushort_t* Slo,
                                            const ushort_t* __restrict__ whi,
                                            const ushort_t* __restrict__ wlo,
                                            int panel, int lane, int q, f32x4 acc[4]) {
    const ushort_t* WH = whi + (size_t)panel * 4096;
    const ushort_t* WL = wlo + (size_t)panel * 4096;
    const int f0 = (q * 64 + lane) * 8;
    const int f1 = ((4 + q) * 64 + lane) * 8;
    bf16x8 bh0 = *(const bf16x8*)(WH + f0);
    bf16x8 bh1 = *(const bf16x8*)(WH + f1);
    bf16x8 bl0 = *(const bf16x8*)(WL + f0);
    bf16x8 bl1 = *(const bf16x8*)(WL + f1);
    const int ar = (lane & 15) * 72 + ((lane >> 4) << 3);
#pragma unroll
    for (int t = 0; t < 4; ++t) {
        const ushort_t* a  = Shi + t * 16 * 72 + ar;
        const ushort_t* al = Slo + t * 16 * 72 + ar;
        bf16x8 ah0 = *(const bf16x8*)(a);
        bf16x8 ah1 = *(const bf16x8*)(a + 32);
        bf16x8 aL0 = *(const bf16x8*)(al);
        bf16x8 aL1 = *(const bf16x8*)(al + 32);
        acc[t] = MFMA16(ah0, bh0, acc[t]);
        acc[t] = MFMA16(ah1, bh1, acc[t]);
        acc[t] = MFMA16(ah0, bl0, acc[t]);
        acc[t] = MFMA16(aL0, bh0, acc[t]);
        acc[t] = MFMA16(ah1, bl1, acc[t]);
        acc[t] = MFMA16(aL1, bh1, acc[t]);
    }
}

// load 16 f32 (guarded) with scale
__device__ __forceinline__ void load16(const float* src, bool valid, float scale,
                                       float v[16]) {
#pragma unroll
    for (int j4 = 0; j4 < 4; ++j4) {
        float4 t = valid ? *(const float4*)(src + j4 * 4) : make_float4(0.f, 0.f, 0.f, 0.f);
        v[j4 * 4 + 0] = t.x * scale;
        v[j4 * 4 + 1] = t.y * scale;
        v[j4 * 4 + 2] = t.z * scale;
        v[j4 * 4 + 3] = t.w * scale;
    }
}

// split 16 floats to bf16 hi/lo and store to S row
__device__ __forceinline__ void split16_store(ushort_t* Shi, ushort_t* Slo,
                                              int row, int c0, const float v[16]) {
    u16x8 ha, la, hb, lb;
#pragma unroll
    for (int j = 0; j < 8; ++j) {
        unsigned uh = bf16_1(v[j]);
        ha[j] = (unsigned short)uh;
        la[j] = (unsigned short)bf16_1(v[j] - __uint_as_float(uh << 16));
    }
#pragma unroll
    for (int j = 0; j < 8; ++j) {
        unsigned uh = bf16_1(v[8 + j]);
        hb[j] = (unsigned short)uh;
        lb[j] = (unsigned short)bf16_1(v[8 + j] - __uint_as_float(uh << 16));
    }
    *(u16x8*)(Shi + row * 72 + c0) = ha;
    *(u16x8*)(Shi + row * 72 + c0 + 8) = hb;
    *(u16x8*)(Slo + row * 72 + c0) = la;
    *(u16x8*)(Slo + row * 72 + c0 + 8) = lb;
}

// epilogue: write acc (optional relu) back into S as split bf16
__device__ __forceinline__ void epi_S(const f32x4 acc[4], bool relu,
                                      ushort_t* Shi, ushort_t* Slo,
                                      int lane, int colL) {
#pragma unroll
    for (int t = 0; t < 4; ++t)
#pragma unroll
        for (int i = 0; i < 4; ++i) {
            int row = t * 16 + ((lane >> 4) << 2) + i;
            float vv = acc[t][i];
            if (relu) vv = fmaxf(vv, 0.f);
            unsigned uh = bf16_1(vv);
            Shi[row * 72 + colL] = (ushort_t)uh;
            Slo[row * 72 + colL] = (ushort_t)bf16_1(vv - __uint_as_float(uh << 16));
        }
}

// h = x@w_in+b_in ; msg16 = relu(relu(h@m1+b1)@m2+b2)
__global__ __launch_bounds__(256, 2) void k_lin_msg(const float* __restrict__ x,
                                                    const ushort_t* __restrict__ whi,
                                                    const ushort_t* __restrict__ wlo,
                                                    const float* __restrict__ b_in,
                                                    const float* __restrict__ m1b,
                                                    const float* __restrict__ m2b,
                                                    float* __restrict__ h,
                                                    ushort_t* __restrict__ msg16) {
    __shared__ ushort_t Shi[64 * 72];
    __shared__ ushort_t Slo[64 * 72];
    const int tid = threadIdx.x;
    const int lane = tid & 63;
    const int q = __builtin_amdgcn_readfirstlane(tid >> 6);
    const int colL = q * 16 + (lane & 15);
    const int r0 = blockIdx.x * 64;
    const int nrows = min(64, N_NODES - r0);
    const int srow = tid >> 2, c0 = (tid & 3) * 16;
    const bool rv = srow < nrows;

    f32x4 acc[4];
    {
        float bj = b_in[colL];
#pragma unroll
        for (int t = 0; t < 4; ++t) acc[t] = (f32x4){bj, bj, bj, bj};
    }
    float v[16];
    // x panel 0 (cols 0-63)
    load16(x + (size_t)(r0 + srow) * 128 + c0, rv, 1.f, v);
    split16_store(Shi, Slo, srow, c0, v);
    __syncthreads();
    mfma_gemm64(Shi, Slo, whi, wlo, 0, lane, q, acc);
    __syncthreads();
    // x panel 1 (cols 64-127)
    load16(x + (size_t)(r0 + srow) * 128 + 64 + c0, rv, 1.f, v);
    split16_store(Shi, Slo, srow, c0, v);
    __syncthreads();
    mfma_gemm64(Shi, Slo, whi, wlo, 1, lane, q, acc);
    __syncthreads();
    // write h + stage h into S
#pragma unroll
    for (int t = 0; t < 4; ++t)
#pragma unroll
        for (int i = 0; i < 4; ++i) {
            int row = t * 16 + ((lane >> 4) << 2) + i;
            int grow = r0 + row;
            if (grow < N_NODES) h[(size_t)grow * 64 + colL] = acc[t][i];
        }
    epi_S(acc, false, Shi, Slo, lane, colL);
    __syncthreads();

    // m1
    {
        float bj = m1b[colL];
#pragma unroll
        for (int t = 0; t < 4; ++t) acc[t] = (f32x4){bj, bj, bj, bj};
    }
    mfma_gemm64(Shi, Slo, whi, wlo, 2, lane, q, acc);
    __syncthreads();
    epi_S(acc, true, Shi, Slo, lane, colL);
    __syncthreads();

    // m2
    {
        float bj = m2b[colL];
#pragma unroll
        for (int t = 0; t < 4; ++t) acc[t] = (f32x4){bj, bj, bj, bj};
    }
    mfma_gemm64(Shi, Slo, whi, wlo, 3, lane, q, acc);
#pragma unroll
    for (int t = 0; t < 4; ++t)
#pragma unroll
        for (int i = 0; i < 4; ++i) {
            int row = t * 16 + ((lane >> 4) << 2) + i;
            int grow = r0 + row;
            if (grow < N_NODES)
                msg16[(size_t)grow * 64 + colL] = (ushort_t)bf16_1(fmaxf(acc[t][i], 0.f));
        }
}

// ============ aggregation: gather, 4 edges per VMEM instruction ============
__global__ __launch_bounds__(256) void k_gather(const int* __restrict__ start,
                                                const int* __restrict__ csr,
                                                const ushort_t* __restrict__ msg16,
                                                float* __restrict__ agg) {
    const int lane = threadIdx.x & 63;
    const int wid  = threadIdx.x >> 6;
    const int q4   = lane >> 4;
    const int s16  = lane & 15;
    int r = blockIdx.x * 4 + wid;
    if (r >= N_NODES) return;
    int b = start[r];
    int e0 = start[r + 1];
    float a0 = 0.f, a1 = 0.f, a2 = 0.f, a3 = 0.f;
    for (int base = b; base < e0; base += 64) {
        int n = e0 - base;
        if (n > 64) n = 64;
        int c = 0;
        if (base + lane < e0) c = csr[base + lane];
#pragma unroll 2
        for (int j = 0; j < n; j += 4) {
            int jj = j + q4;
            bool act = jj < n;
            int cj = __shfl(c, act ? jj : 0, 64);
            ushort4 v = *(const ushort4*)(msg16 + (size_t)cj * 64 + s16 * 4);
            if (act) {
                a0 += bf16_f(v.x);
                a1 += bf16_f(v.y);
                a2 += bf16_f(v.z);
                a3 += bf16_f(v.w);
            }
        }
    }
    a0 += __shfl_xor(a0, 16, 64); a0 += __shfl_xor(a0, 32, 64);
    a1 += __shfl_xor(a1, 16, 64); a1 += __shfl_xor(a1, 32, 64);
    a2 += __shfl_xor(a2, 16, 64); a2 += __shfl_xor(a2, 32, 64);
    a3 += __shfl_xor(a3, 16, 64); a3 += __shfl_xor(a3, 32, 64);
    if (q4 == 0)
        *(float4*)(agg + (size_t)r * 64 + s16 * 4) = make_float4(a0, a1, a2, a3);
}

// ---- update layer0 then msg layer1 (MFMA) ----
__global__ __launch_bounds__(256, 2) void k_update_msg(float* __restrict__ h,
                                                       const float* __restrict__ agg,
                                                       const int* __restrict__ start,
                                                       const ushort_t* __restrict__ whi,
                                                       const ushort_t* __restrict__ wlo,
                                                       const float* __restrict__ b1,
                                                       const float* __restrict__ b2,
                                                       const float* __restrict__ m1b,
                                                       const float* __restrict__ m2b,
                                                       ushort_t* __restrict__ msg16) {
    __shared__ ushort_t Shi[64 * 72];
    __shared__ ushort_t Slo[64 * 72];
    const int tid = threadIdx.x;
    const int lane = tid & 63;
    const int q = __builtin_amdgcn_readfirstlane(tid >> 6);
    const int colL = q * 16 + (lane & 15);
    const int r0 = blockIdx.x * 64;
    const int nrows = min(64, N_NODES - r0);
    const int srow = tid >> 2, c0 = (tid & 3) * 16;
    const bool rv = srow < nrows;

    f32x4 acc[4];
    {
        float bj = b1[colL];
#pragma unroll
        for (int t = 0; t < 4; ++t) acc[t] = (f32x4){bj, bj, bj, bj};
    }
    float v[16];
    // u1 agg part (panel 5): stage agg * inv(deg)
    {
        float invS = 0.f;
        if (rv) {
            int g = r0 + srow;
            invS = 1.f / fmaxf((float)(start[g + 1] - start[g]), 1.f);
        }
        load16(agg + (size_t)(r0 + srow) * 64 + c0, rv, invS, v);
        split16_store(Shi, Slo, srow, c0, v);
    }
    __syncthreads();
    mfma_gemm64(Shi, Slo, whi, wlo, 5, lane, q, acc);
    __syncthreads();
    // u1 h part (panel 4)
    load16(h + (size_t)(r0 + srow) * 64 + c0, rv, 1.f, v);
    split16_store(Shi, Slo, srow, c0, v);
    __syncthreads();
    mfma_gemm64(Shi, Slo, whi, wlo, 4, lane, q, acc);
    // residual grab while S holds h (bf16-split, err ~2^-18)
    float res[16];
#pragma unroll
    for (int t = 0; t < 4; ++t)
#pragma unroll
        for (int i = 0; i < 4; ++i) {
            int row = t * 16 + ((lane >> 4) << 2) + i;
            res[t * 4 + i] = bf16_f(Shi[row * 72 + colL]) + bf16_f(Slo[row * 72 + colL]);
        }
    __syncthreads();
    epi_S(acc, true, Shi, Slo, lane, colL);
    __syncthreads();

    // u2 (panel 6) + residual -> h_new
    {
        float bj = b2[colL];
#pragma unroll
        for (int t = 0; t < 4; ++t) acc[t] = (f32x4){bj, bj, bj, bj};
    }
    mfma_gemm64(Shi, Slo, whi, wlo, 6, lane, q, acc);
    __syncthreads();
#pragma unroll
    for (int t = 0; t < 4; ++t)
#pragma unroll
        for (int i = 0; i < 4; ++i) {
            int row = t * 16 + ((lane >> 4) << 2) + i;
            float vv = acc[t][i] + res[t * 4 + i];
            int grow = r0 + row;
            if (grow < N_NODES) h[(size_t)grow * 64 + colL] = vv;
            unsigned uh = bf16_1(vv);
            Shi[row * 72 + colL] = (ushort_t)uh;
            Slo[row * 72 + colL] = (ushort_t)bf16_1(vv - __uint_as_float(uh << 16));
        }
    __syncthreads();

    // m1 (panel 7)
    {
        float bj = m1b[colL];
#pragma unroll
        for (int t = 0; t < 4; ++t) acc[t] = (f32x4){bj, bj, bj, bj};
    }
    mfma_gemm64(Shi, Slo, whi, wlo, 7, lane, q, acc);
    __syncthreads();
    epi_S(acc, true, Shi, Slo, lane, colL);
    __syncthreads();

    // m2 (panel 8)
    {
        float bj = m2b[colL];
#pragma unroll
        for (int t = 0; t < 4; ++t) acc[t] = (f32x4){bj, bj, bj, bj};
    }
    mfma_gemm64(Shi, Slo, whi, wlo, 8, lane, q, acc);
#pragma unroll
    for (int t = 0; t < 4; ++t)
#pragma unroll
        for (int i = 0; i < 4; ++i) {
            int row = t * 16 + ((lane >> 4) << 2) + i;
            int grow = r0 + row;
            if (grow < N_NODES)
                msg16[(size_t)grow * 64 + colL] = (ushort_t)bf16_1(fmaxf(acc[t][i], 0.f));
        }
}

// ---- update layer1 then head precompute (MFMA) ----
__global__ __launch_bounds__(256, 2) void k_update_headpre(const float* __restrict__ h,
                                                           const float* __restrict__ agg,
                                                           const int* __restrict__ start,
                                                           const ushort_t* __restrict__ whi,
                                                           const ushort_t* __restrict__ wlo,
                                                           const float* __restrict__ b1,
                                                           const float* __restrict__ b2,
                                                           const float* __restrict__ h1w,
                                                           const float* __restrict__ hb1,
                                                           ushort_t* __restrict__ hA16,
                                                           ushort_t* __restrict__ hB16) {
    __shared__ ushort_t Shi[64 * 72];
    __shared__ ushort_t Slo[64 * 72];
    __shared__ float degS[64];
    const int tid = threadIdx.x;
    const int lane = tid & 63;
    const int q = __builtin_amdgcn_readfirstlane(tid >> 6);
    const int colL = q * 16 + (lane & 15);
    const int r0 = blockIdx.x * 64;
    const int nrows = min(64, N_NODES - r0);
    const int srow = tid >> 2, c0 = (tid & 3) * 16;
    const bool rv = srow < nrows;

    if (tid < 64) {
        int g = r0 + tid;
        degS[tid] = (g < N_NODES) ? (float)(start[g + 1] - start[g]) : 0.f;
    }
    __syncthreads();

    f32x4 acc[4];
    {
        float bj = b1[colL];
#pragma unroll
        for (int t = 0; t < 4; ++t) acc[t] = (f32x4){bj, bj, bj, bj};
    }
    float v[16];
    // u1 agg part (panel 10)
    {
        float invS = rv ? (1.f / fmaxf(degS[srow], 1.f)) : 0.f;
        load16(agg + (size_t)(r0 + srow) * 64 + c0, rv, invS, v);
        split16_store(Shi, Slo, srow, c0, v);
    }
    __syncthreads();
    mfma_gemm64(Shi, Slo, whi, wlo, 10, lane, q, acc);
    __syncthreads();
    // u1 h part (panel 9)
    load16(h + (size_t)(r0 + srow) * 64 + c0, rv, 1.f, v);
    split16_store(Shi, Slo, srow, c0, v);
    __syncthreads();
    mfma_gemm64(Shi, Slo, whi, wlo, 9, lane, q, acc);
    float res[16];
#pragma unroll
    for (int t = 0; t < 4; ++t)
#pragma unroll
        for (int i = 0; i < 4; ++i) {
            int row = t * 16 + ((lane >> 4) << 2) + i;
            res[t * 4 + i] = bf16_f(Shi[row * 72 + colL]) + bf16_f(Slo[row * 72 + colL]);
        }
    __syncthreads();
    epi_S(acc, true, Shi, Slo, lane, colL);
    __syncthreads();

    // u2 (panel 11) + residual -> h_new (stays in LDS only)
    {
        float bj = b2[colL];
#pragma unroll
        for (int t = 0; t < 4; ++t) acc[t] = (f32x4){bj, bj, bj, bj};
    }
    mfma_gemm64(Shi, Slo, whi, wlo, 11, lane, q, acc);
    __syncthreads();
#pragma unroll
    for (int t = 0; t < 4; ++t)
#pragma unroll
        for (int i = 0; i < 4; ++i) {
            int row = t * 16 + ((lane >> 4) << 2) + i;
            float vv = acc[t][i] + res[t * 4 + i];
            unsigned uh = bf16_1(vv);
            Shi[row * 72 + colL] = (ushort_t)uh;
            Slo[row * 72 + colL] = (ushort_t)bf16_1(vv - __uint_as_float(uh << 16));
        }
    __syncthreads();

    const float hb1c  = hb1[colL];
    const float w128c = h1w[128 * 64 + colL];
    const float w129c = h1w[129 * 64 + colL];

    // headpre A (panel 12)
#pragma unroll
    for (int t = 0; t < 4; ++t)
#pragma unroll
        for (int i = 0; i < 4; ++i) {
            int row = t * 16 + ((lane >> 4) << 2) + i;
            acc[t][i] = hb1c + degS[row] * w128c;
        }
    mfma_gemm64(Shi, Slo, whi, wlo, 12, lane, q, acc);
#pragma unroll
    for (int t = 0; t < 4; ++t)
#pragma unroll
        for (int i = 0; i < 4; ++i) {
            int row = t * 16 + ((lane >> 4) << 2) + i;
            int grow = r0 + row;
            if (grow < N_NODES)
                hA16[(size_t)grow * 64 + colL] = (ushort_t)bf16_1(acc[t][i]);
        }

    // headpre B (panel 13) — S unchanged, no barrier needed
#pragma unroll
    for (int t = 0; t < 4; ++t)
#pragma unroll
        for (int i = 0; i < 4; ++i) {
            int row = t * 16 + ((lane >> 4) << 2) + i;
            acc[t][i] = degS[row] * w129c;
        }
    mfma_gemm64(Shi, Slo, whi, wlo, 13, lane, q, acc);
#pragma unroll
    for (int t = 0; t < 4; ++t)
#pragma unroll
        for (int i = 0; i < 4; ++i) {
            int row = t * 16 + ((lane >> 4) << 2) + i;
            int grow = r0 + row;
            if (grow < N_NODES)
                hB16[(size_t)grow * 64 + colL] = (ushort_t)bf16_1(acc[t][i]);
        }
}

// ------- out[e] = out[e+HALF] = softplus(relu(hA[src]+hB[dst]) . h2w + h2b) + 1e-6 ------
__global__ __launch_bounds__(256) void k_head(const int* __restrict__ rowIdx,
                                              const int* __restrict__ colIdx,
                                              const ushort_t* __restrict__ hA16,
                                              const ushort_t* __restrict__ hB16,
                                              const float* __restrict__ w2,
                                              const float* __restrict__ b2,
                                              float* __restrict__ out) {
    const int lane = threadIdx.x & 63;
    const int sub = lane & 15;
    const int grp = lane >> 4;
    const int waveId = (blockIdx.x * 256 + threadIdx.x) >> 6;
    const int step = gridDim.x * 4 * 4;
    const float4 wv = *(const float4*)(w2 + sub * 4);
    const float b2v = b2[0];
    for (int e = waveId * 4 + grp; e < HALF_E; e += step) {
        int s = rowIdx[e];
        int d = colIdx[e];
        ushort4 a4 = *(const ushort4*)(hA16 + (size_t)s * 64 + sub * 4);
        ushort4 b4 = *(const ushort4*)(hB16 + (size_t)d * 64 + sub * 4);
        float t0 = fmaxf(bf16_f(a4.x) + bf16_f(b4.x), 0.0f);
        float t1 = fmaxf(bf16_f(a4.y) + bf16_f(b4.y), 0.0f);
        float t2 = fmaxf(bf16_f(a4.z) + bf16_f(b4.z), 0.0f);
        float t3 = fmaxf(bf16_f(a4.w) + bf16_f(b4.w), 0.0f);
        float p = t0 * wv.x + t1 * wv.y + t2 * wv.z + t3 * wv.w;
        p += __shfl_xor(p, 1);
        p += __shfl_xor(p, 2);
        p += __shfl_xor(p, 4);
        p += __shfl_xor(p, 8);
        if (sub == 0) {
            float sv = p + b2v;
            float sp = fmaxf(sv, 0.0f) + log1pf(expf(-fabsf(sv)));
            float wvv = sp + 1e-6f;
            out[e] = wvv;
            out[e + HALF_E] = wvv;
        }
    }
}

extern "C" void kernel_launch(void* const* d_in, const int* in_sizes, int n_in,
                              void* d_out, int out_size, void* d_ws, size_t ws_size,
                              hipStream_t stream) {
    const float* x      = (const float*)d_in[0];
    const int*   rowIdx = (const int*)d_in[1];
    const int*   colIdx = rowIdx + E_EDGES;
    const float* w_in   = (const float*)d_in[2];
    const float* b_in   = (const float*)d_in[3];
    const float* l0_m1w = (const float*)d_in[4];
    const float* l0_m1b = (const float*)d_in[5];
    const float* l0_m2w = (const float*)d_in[6];
    const float* l0_m2b = (const float*)d_in[7];
    const float* l0_u1w = (const float*)d_in[8];
    const float* l0_u1b = (const float*)d_in[9];
    const float* l0_u2w = (const float*)d_in[10];
    const float* l0_u2b = (const float*)d_in[11];
    const float* l1_m1w = (const float*)d_in[12];
    const float* l1_m1b = (const float*)d_in[13];
    const float* l1_m2w = (const float*)d_in[14];
    const float* l1_m2b = (const float*)d_in[15];
    const float* l1_u1w = (const float*)d_in[16];
    const float* l1_u1b = (const float*)d_in[17];
    const float* l1_u2w = (const float*)d_in[18];
    const float* l1_u2b = (const float*)d_in[19];
    const float* h1w    = (const float*)d_in[20];
    const float* h1b    = (const float*)d_in[21];
    const float* h2w    = (const float*)d_in[22];
    const float* h2b    = (const float*)d_in[23];

    float* out = (float*)d_out;

    float*    h     = (float*)d_ws;                         // N x 64 f32
    float*    agg   = h + (size_t)N_NODES * 64;             // N x 64 f32
    ushort_t* msg16 = (ushort_t*)(agg + (size_t)N_NODES * 64); // N x 64 bf16
    ushort_t* hB16  = msg16 + (size_t)N_NODES * 64;         // N x 64 bf16
    int*      start = (int*)(hB16 + (size_t)N_NODES * 64);  // N + 1
    int*      bcnt  = start + N_NODES + 1;                  // 256
    int*      bbase = bcnt + NBUCK;                         // 257 (pad 32)
    int*      curA  = bbase + NBUCK + 32;                   // 256
    int*      csr   = curA + NBUCK;                         // E
    ushort_t* whi   = (ushort_t*)(csr + E_EDGES);           // 14*4096 bf16
    ushort_t* wlo   = whi + 14 * 4096;                      // 14*4096 bf16
    uint2*    pairs = (uint2*)agg;                          // alias: dead before gather writes agg
    ushort_t* hA16  = msg16;                                // alias: msg16 dead after gather1

    const int nb64 = (N_NODES + 63) / 64;                   // 1563 blocks for MLP kernels
    const int gatherBlocks = (N_NODES + 3) / 4;

    // ---- CSR build + weight split ----
    hipMemsetAsync(bcnt, 0, NBUCK * sizeof(int), stream);
    k_bhist<<<2048, 256, 0, stream>>>(rowIdx, bcnt);
    k_bscan256<<<1, 256, 0, stream>>>(bcnt, bbase, curA, start);
    k_bucketA<<<NBLK_A, 256, 0, stream>>>(rowIdx, colIdx, curA, pairs);
    k_bucketB<<<NBUCK, 256, 0, stream>>>(bbase, pairs, start, csr);
    k_wsplit<<<14, 512, 0, stream>>>(w_in, l0_m1w, l0_m2w, l0_u1w, l0_u2w,
                                     l1_m1w, l1_m2w, l1_u1w, l1_u2w, h1w, whi, wlo);

    // ---- input linear + layer0 message ----
    k_lin_msg<<<nb64, 256, 0, stream>>>(x, whi, wlo, b_in, l0_m1b, l0_m2b, h, msg16);
    // ---- layer 0 ----
    k_gather<<<gatherBlocks, 256, 0, stream>>>(start, csr, msg16, agg);
    k_update_msg<<<nb64, 256, 0, stream>>>(h, agg, start, whi, wlo,
                                           l0_u1b, l0_u2b, l1_m1b, l1_m2b, msg16);
    // ---- layer 1 ----
    k_gather<<<gatherBlocks, 256, 0, stream>>>(start, csr, msg16, agg);
    k_update_headpre<<<nb64, 256, 0, stream>>>(h, agg, start, whi, wlo,
                                               l1_u1b, l1_u2b, h1w, h1b, hA16, hB16);
    // ---- head ----
    k_head<<<4096, 256, 0, stream>>>(rowIdx, colIdx, hA16, hB16, h2w, h2b, out);
}

// Round 13
// 280.750 us; speedup vs baseline: 1.7726x; 1.1770x over previous
//
#include <hip/hip_runtime.h>
#include <math.h>

#define N_NODES 100000
#define E_EDGES 1600000
#define HALF_E  (E_EDGES / 2)

#define NBUCK 256
#define ROWS_PER_BUCKET ((N_NODES + NBUCK - 1) / NBUCK)   // 391
#define EDGES_PER_BLK_A 4096
#define NBLK_A ((E_EDGES + EDGES_PER_BLK_A - 1) / EDGES_PER_BLK_A)  // 391
#define NBH_BLOCKS 256

typedef unsigned short ushort_t;
typedef __attribute__((ext_vector_type(8))) short bf16x8;
typedef __attribute__((ext_vector_type(8))) unsigned short u16x8;
typedef __attribute__((ext_vector_type(4))) float f32x4;

#define MFMA16(a, b, c) __builtin_amdgcn_mfma_f32_16x16x32_bf16(a, b, c, 0, 0, 0)

// ---- bf16 helpers (RNE pack, cheap unpack) ----
__device__ __forceinline__ unsigned bf16_1(float f) {
    unsigned u = __float_as_uint(f);
    return (u + 0x7fffu + ((u >> 16) & 1u)) >> 16;
}
__device__ __forceinline__ float bf16_f(ushort_t us) {
    return __uint_as_float(((unsigned)us) << 16);
}

// ============ CSR build (bucketed) ============

// per-block partial histograms (no global atomics)
__global__ __launch_bounds__(256) void k_bhist(const int* __restrict__ rowIdx,
                                               int* __restrict__ part) {
    __shared__ int c[NBUCK];
    const int tid = threadIdx.x;
    c[tid] = 0;
    __syncthreads();
    for (int e = blockIdx.x * 256 + tid; e < E_EDGES; e += NBH_BLOCKS * 256)
        atomicAdd(&c[rowIdx[e] / ROWS_PER_BUCKET], 1);
    __syncthreads();
    part[blockIdx.x * NBUCK + tid] = c[tid];
}

// column-sum partials, then exclusive scan -> bbase[257]; seed curA, start[N]
__global__ __launch_bounds__(256) void k_bscan256(const int* __restrict__ part,
                                                  int* __restrict__ bbase,
                                                  int* __restrict__ curA,
                                                  int* __restrict__ start) {
    __shared__ int sc[NBUCK];
    const int tid = threadIdx.x;
    int v = 0;
    for (int b = 0; b < NBH_BLOCKS; ++b) v += part[b * NBUCK + tid];
    sc[tid] = v;
    __syncthreads();
    for (int st = 1; st < 256; st <<= 1) {
        int t = (tid >= st) ? sc[tid - st] : 0;
        __syncthreads();
        sc[tid] += t;
        __syncthreads();
    }
    int excl = sc[tid] - v;
    bbase[tid] = excl;
    curA[tid] = excl;
    if (tid == 255) bbase[256] = sc[255];
    if (tid == 0) start[N_NODES] = E_EDGES;
}

__global__ __launch_bounds__(256) void k_bucketA(const int* __restrict__ rowIdx,
                                                 const int* __restrict__ colIdx,
                                                 int* __restrict__ cursorA,
                                                 uint2* __restrict__ pairs) {
    __shared__ uint2 stage[EDGES_PER_BLK_A];
    __shared__ unsigned char bmap[EDGES_PER_BLK_A];
    __shared__ int cntL[NBUCK], scanEx[NBUCK], cur[NBUCK], posG[NBUCK];
    const int tid = threadIdx.x;
    const int e0 = blockIdx.x * EDGES_PER_BLK_A;
    const int n = min(EDGES_PER_BLK_A, E_EDGES - e0);

    cntL[tid] = 0;
    __syncthreads();
    for (int i = tid; i < n; i += 256) {
        int b = rowIdx[e0 + i] / ROWS_PER_BUCKET;
        atomicAdd(&cntL[b], 1);
    }
    __syncthreads();
    int myc = cntL[tid];
    scanEx[tid] = myc;
    __syncthreads();
    for (int st = 1; st < 256; st <<= 1) {
        int t = (tid >= st) ? scanEx[tid - st] : 0;
        __syncthreads();
        scanEx[tid] += t;
        __syncthreads();
    }
    int ex = scanEx[tid] - myc;
    __syncthreads();
    scanEx[tid] = ex;
    cur[tid] = ex;
    if (myc) posG[tid] = atomicAdd(&cursorA[tid], myc);
    __syncthreads();
    for (int i = tid; i < n; i += 256) {
        int r = rowIdx[e0 + i];
        int c = colIdx[e0 + i];
        int b = r / ROWS_PER_BUCKET;
        int slot = atomicAdd(&cur[b], 1);
        stage[slot] = make_uint2((unsigned)c, (unsigned)r);
        bmap[slot] = (unsigned char)b;
    }
    __syncthreads();
    for (int i = tid; i < n; i += 256) {
        int b = bmap[i];
        int dst = posG[b] + (i - scanEx[b]);
        pairs[dst] = stage[i];
    }
}

__global__ __launch_bounds__(256) void k_bucketB(const int* __restrict__ bbase,
                                                 const uint2* __restrict__ pairs,
                                                 int* __restrict__ start,
                                                 int* __restrict__ csr) {
    __shared__ int cur[ROWS_PER_BUCKET];
    __shared__ int scn[512];
    const int tid = threadIdx.x;
    const int rowbase = blockIdx.x * ROWS_PER_BUCKET;
    const int nrows = min(ROWS_PER_BUCKET, N_NODES - rowbase);
    for (int i = tid; i < nrows; i += 256) cur[i] = 0;
    __syncthreads();
    const int bBeg = bbase[blockIdx.x];
    const int bEnd = bbase[blockIdx.x + 1];
    for (int i = bBeg + tid; i < bEnd; i += 256)
        atomicAdd(&cur[(int)pairs[i].y - rowbase], 1);
    __syncthreads();
    scn[tid] = (tid < nrows) ? cur[tid] : 0;
    scn[tid + 256] = (tid + 256 < nrows) ? cur[tid + 256] : 0;
    __syncthreads();
    for (int st = 1; st < 512; st <<= 1) {
        int i0 = tid, i1 = tid + 256;
        int t0 = (i0 >= st) ? scn[i0 - st] : 0;
        int t1 = (i1 >= st) ? scn[i1 - st] : 0;
        __syncthreads();
        scn[i0] += t0;
        scn[i1] += t1;
        __syncthreads();
    }
    for (int i = tid; i < nrows; i += 256) {
        int sv = bBeg + scn[i] - cur[i];
        start[rowbase + i] = sv;
        cur[i] = sv;
    }
    __syncthreads();
    for (int i = bBeg + tid; i < bEnd; i += 256) {
        uint2 p = pairs[i];
        int pos = atomicAdd(&cur[(int)p.y - rowbase], 1);
        csr[pos] = (int)p.x;
    }
}

// ============ weight split (fp32 -> fragment-layout bf16 hi/lo) ============
__global__ __launch_bounds__(512) void k_wsplit(const float* __restrict__ w_in,
                                                const float* __restrict__ l0_m1w,
                                                const float* __restrict__ l0_m2w,
                                                const float* __restrict__ l0_u1w,
                                                const float* __restrict__ l0_u2w,
                                                const float* __restrict__ l1_m1w,
                                                const float* __restrict__ l1_m2w,
                                                const float* __restrict__ l1_u1w,
                                                const float* __restrict__ l1_u2w,
                                                const float* __restrict__ h1w,
                                                ushort_t* __restrict__ whi,
                                                ushort_t* __restrict__ wlo) {
    const float* src;
    switch (blockIdx.x) {
        case 0:  src = w_in;           break;
        case 1:  src = w_in + 4096;    break;
        case 2:  src = l0_m1w;         break;
        case 3:  src = l0_m2w;         break;
        case 4:  src = l0_u1w;         break;
        case 5:  src = l0_u1w + 4096;  break;
        case 6:  src = l0_u2w;         break;
        case 7:  src = l1_m1w;         break;
        case 8:  src = l1_m2w;         break;
        case 9:  src = l1_u1w;         break;
        case 10: src = l1_u1w + 4096;  break;
        case 11: src = l1_u2w;         break;
        case 12: src = h1w;            break;
        default: src = h1w + 4096;     break;
    }
    const int tid = threadIdx.x;
    const int h = tid >> 8;
    const int c = (tid >> 6) & 3;
    const int lane = tid & 63;
    const int kg = lane >> 4, lr = lane & 15;
    const int col = c * 16 + lr;
    u16x8 hi8, lo8;
#pragma unroll
    for (int j = 0; j < 8; ++j) {
        int k = h * 32 + kg * 8 + j;
        float v = src[k * 64 + col];
        unsigned uh = bf16_1(v);
        hi8[j] = (unsigned short)uh;
        lo8[j] = (unsigned short)bf16_1(v - __uint_as_float(uh << 16));
    }
    size_t idx = (size_t)blockIdx.x * 4096 + ((size_t)(h * 4 + c) * 64 + lane) * 8;
    *(u16x8*)(whi + idx) = hi8;
    *(u16x8*)(wlo + idx) = lo8;
}

// ============ MFMA node-MLP machinery ============

__device__ __forceinline__ void mfma_gemm64(const ushort_t* Shi, const ushort_t* Slo,
                                            const ushort_t* __restrict__ whi,
                                            const ushort_t* __restrict__ wlo,
                                            int panel, int lane, int q, f32x4 acc[4]) {
    const ushort_t* WH = whi + (size_t)panel * 4096;
    const ushort_t* WL = wlo + (size_t)panel * 4096;
    const int f0 = (q * 64 + lane) * 8;
    const int f1 = ((4 + q) * 64 + lane) * 8;
    bf16x8 bh0 = *(const bf16x8*)(WH + f0);
    bf16x8 bh1 = *(const bf16x8*)(WH + f1);
    bf16x8 bl0 = *(const bf16x8*)(WL + f0);
    bf16x8 bl1 = *(const bf16x8*)(WL + f1);
    const int ar = (lane & 15) * 72 + ((lane >> 4) << 3);
#pragma unroll
    for (int t = 0; t < 4; ++t) {
        const ushort_t* a  = Shi + t * 16 * 72 + ar;
        const ushort_t* al = Slo + t * 16 * 72 + ar;
        bf16x8 ah0 = *(const bf16x8*)(a);
        bf16x8 ah1 = *(const bf16x8*)(a + 32);
        bf16x8 aL0 = *(const bf16x8*)(al);
        bf16x8 aL1 = *(const bf16x8*)(al + 32);
        acc[t] = MFMA16(ah0, bh0, acc[t]);
        acc[t] = MFMA16(ah1, bh1, acc[t]);
        acc[t] = MFMA16(ah0, bl0, acc[t]);
        acc[t] = MFMA16(aL0, bh0, acc[t]);
        acc[t] = MFMA16(ah1, bl1, acc[t]);
        acc[t] = MFMA16(aL1, bh1, acc[t]);
    }
}

__device__ __forceinline__ void load16(const float* src, bool valid, float scale,
                                       float v[16]) {
#pragma unroll
    for (int j4 = 0; j4 < 4; ++j4) {
        float4 t = valid ? *(const float4*)(src + j4 * 4) : make_float4(0.f, 0.f, 0.f, 0.f);
        v[j4 * 4 + 0] = t.x * scale;
        v[j4 * 4 + 1] = t.y * scale;
        v[j4 * 4 + 2] = t.z * scale;
        v[j4 * 4 + 3] = t.w * scale;
    }
}

__device__ __forceinline__ void split16_store(ushort_t* Shi, ushort_t* Slo,
                                              int row, int c0, const float v[16]) {
    u16x8 ha, la, hb, lb;
#pragma unroll
    for (int j = 0; j < 8; ++j) {
        unsigned uh = bf16_1(v[j]);
        ha[j] = (unsigned short)uh;
        la[j] = (unsigned short)bf16_1(v[j] - __uint_as_float(uh << 16));
    }
#pragma unroll
    for (int j = 0; j < 8; ++j) {
        unsigned uh = bf16_1(v[8 + j]);
        hb[j] = (unsigned short)uh;
        lb[j] = (unsigned short)bf16_1(v[8 + j] - __uint_as_float(uh << 16));
    }
    *(u16x8*)(Shi + row * 72 + c0) = ha;
    *(u16x8*)(Shi + row * 72 + c0 + 8) = hb;
    *(u16x8*)(Slo + row * 72 + c0) = la;
    *(u16x8*)(Slo + row * 72 + c0 + 8) = lb;
}

__device__ __forceinline__ void epi_S(const f32x4 acc[4], bool relu,
                                      ushort_t* Shi, ushort_t* Slo,
                                      int lane, int colL) {
#pragma unroll
    for (int t = 0; t < 4; ++t)
#pragma unroll
        for (int i = 0; i < 4; ++i) {
            int row = t * 16 + ((lane >> 4) << 2) + i;
            float vv = acc[t][i];
            if (relu) vv = fmaxf(vv, 0.f);
            unsigned uh = bf16_1(vv);
            Shi[row * 72 + colL] = (ushort_t)uh;
            Slo[row * 72 + colL] = (ushort_t)bf16_1(vv - __uint_as_float(uh << 16));
        }
}

// h = x@w_in+b_in ; msg16 = relu(relu(h@m1+b1)@m2+b2)
__global__ __launch_bounds__(256, 2) void k_lin_msg(const float* __restrict__ x,
                                                    const ushort_t* __restrict__ whi,
                                                    const ushort_t* __restrict__ wlo,
                                                    const float* __restrict__ b_in,
                                                    const float* __restrict__ m1b,
                                                    const float* __restrict__ m2b,
                                                    float* __restrict__ h,
                                                    ushort_t* __restrict__ msg16) {
    __shared__ ushort_t Shi[64 * 72];
    __shared__ ushort_t Slo[64 * 72];
    const int tid = threadIdx.x;
    const int lane = tid & 63;
    const int q = __builtin_amdgcn_readfirstlane(tid >> 6);
    const int colL = q * 16 + (lane & 15);
    const int r0 = blockIdx.x * 64;
    const int nrows = min(64, N_NODES - r0);
    const int srow = tid >> 2, c0 = (tid & 3) * 16;
    const bool rv = srow < nrows;

    f32x4 acc[4];
    {
        float bj = b_in[colL];
#pragma unroll
        for (int t = 0; t < 4; ++t) acc[t] = (f32x4){bj, bj, bj, bj};
    }
    float v[16];
    load16(x + (size_t)(r0 + srow) * 128 + c0, rv, 1.f, v);
    split16_store(Shi, Slo, srow, c0, v);
    __syncthreads();
    mfma_gemm64(Shi, Slo, whi, wlo, 0, lane, q, acc);
    __syncthreads();
    load16(x + (size_t)(r0 + srow) * 128 + 64 + c0, rv, 1.f, v);
    split16_store(Shi, Slo, srow, c0, v);
    __syncthreads();
    mfma_gemm64(Shi, Slo, whi, wlo, 1, lane, q, acc);
    __syncthreads();
#pragma unroll
    for (int t = 0; t < 4; ++t)
#pragma unroll
        for (int i = 0; i < 4; ++i) {
            int row = t * 16 + ((lane >> 4) << 2) + i;
            int grow = r0 + row;
            if (grow < N_NODES) h[(size_t)grow * 64 + colL] = acc[t][i];
        }
    epi_S(acc, false, Shi, Slo, lane, colL);
    __syncthreads();

    {
        float bj = m1b[colL];
#pragma unroll
        for (int t = 0; t < 4; ++t) acc[t] = (f32x4){bj, bj, bj, bj};
    }
    mfma_gemm64(Shi, Slo, whi, wlo, 2, lane, q, acc);
    __syncthreads();
    epi_S(acc, true, Shi, Slo, lane, colL);
    __syncthreads();

    {
        float bj = m2b[colL];
#pragma unroll
        for (int t = 0; t < 4; ++t) acc[t] = (f32x4){bj, bj, bj, bj};
    }
    mfma_gemm64(Shi, Slo, whi, wlo, 3, lane, q, acc);
#pragma unroll
    for (int t = 0; t < 4; ++t)
#pragma unroll
        for (int i = 0; i < 4; ++i) {
            int row = t * 16 + ((lane >> 4) << 2) + i;
            int grow = r0 + row;
            if (grow < N_NODES)
                msg16[(size_t)grow * 64 + colL] = (ushort_t)bf16_1(fmaxf(acc[t][i], 0.f));
        }
}

// ============ aggregation: gather, 4 edges per VMEM instruction ============
__global__ __launch_bounds__(256) void k_gather(const int* __restrict__ start,
                                                const int* __restrict__ csr,
                                                const ushort_t* __restrict__ msg16,
                                                float* __restrict__ agg) {
    const int lane = threadIdx.x & 63;
    const int wid  = threadIdx.x >> 6;
    const int q4   = lane >> 4;
    const int s16  = lane & 15;
    int r = blockIdx.x * 4 + wid;
    if (r >= N_NODES) return;
    int b = start[r];
    int e0 = start[r + 1];
    float a0 = 0.f, a1 = 0.f, a2 = 0.f, a3 = 0.f;
    for (int base = b; base < e0; base += 64) {
        int n = e0 - base;
        if (n > 64) n = 64;
        int c = 0;
        if (base + lane < e0) c = csr[base + lane];
#pragma unroll 2
        for (int j = 0; j < n; j += 4) {
            int jj = j + q4;
            bool act = jj < n;
            int cj = __shfl(c, act ? jj : 0, 64);
            ushort4 v = *(const ushort4*)(msg16 + (size_t)cj * 64 + s16 * 4);
            if (act) {
                a0 += bf16_f(v.x);
                a1 += bf16_f(v.y);
                a2 += bf16_f(v.z);
                a3 += bf16_f(v.w);
            }
        }
    }
    a0 += __shfl_xor(a0, 16, 64); a0 += __shfl_xor(a0, 32, 64);
    a1 += __shfl_xor(a1, 16, 64); a1 += __shfl_xor(a1, 32, 64);
    a2 += __shfl_xor(a2, 16, 64); a2 += __shfl_xor(a2, 32, 64);
    a3 += __shfl_xor(a3, 16, 64); a3 += __shfl_xor(a3, 32, 64);
    if (q4 == 0)
        *(float4*)(agg + (size_t)r * 64 + s16 * 4) = make_float4(a0, a1, a2, a3);
}

// ---- update layer0 then msg layer1 (MFMA) ----
__global__ __launch_bounds__(256, 2) void k_update_msg(float* __restrict__ h,
                                                       const float* __restrict__ agg,
                                                       const int* __restrict__ start,
                                                       const ushort_t* __restrict__ whi,
                                                       const ushort_t* __restrict__ wlo,
                                                       const float* __restrict__ b1,
                                                       const float* __restrict__ b2,
                                                       const float* __restrict__ m1b,
                                                       const float* __restrict__ m2b,
                                                       ushort_t* __restrict__ msg16) {
    __shared__ ushort_t Shi[64 * 72];
    __shared__ ushort_t Slo[64 * 72];
    const int tid = threadIdx.x;
    const int lane = tid & 63;
    const int q = __builtin_amdgcn_readfirstlane(tid >> 6);
    const int colL = q * 16 + (lane & 15);
    const int r0 = blockIdx.x * 64;
    const int nrows = min(64, N_NODES - r0);
    const int srow = tid >> 2, c0 = (tid & 3) * 16;
    const bool rv = srow < nrows;

    f32x4 acc[4];
    {
        float bj = b1[colL];
#pragma unroll
        for (int t = 0; t < 4; ++t) acc[t] = (f32x4){bj, bj, bj, bj};
    }
    float v[16];
    {
        float invS = 0.f;
        if (rv) {
            int g = r0 + srow;
            invS = 1.f / fmaxf((float)(start[g + 1] - start[g]), 1.f);
        }
        load16(agg + (size_t)(r0 + srow) * 64 + c0, rv, invS, v);
        split16_store(Shi, Slo, srow, c0, v);
    }
    __syncthreads();
    mfma_gemm64(Shi, Slo, whi, wlo, 5, lane, q, acc);
    __syncthreads();
    load16(h + (size_t)(r0 + srow) * 64 + c0, rv, 1.f, v);
    split16_store(Shi, Slo, srow, c0, v);
    __syncthreads();
    mfma_gemm64(Shi, Slo, whi, wlo, 4, lane, q, acc);
    float res[16];
#pragma unroll
    for (int t = 0; t < 4; ++t)
#pragma unroll
        for (int i = 0; i < 4; ++i) {
            int row = t * 16 + ((lane >> 4) << 2) + i;
            res[t * 4 + i] = bf16_f(Shi[row * 72 + colL]) + bf16_f(Slo[row * 72 + colL]);
        }
    __syncthreads();
    epi_S(acc, true, Shi, Slo, lane, colL);
    __syncthreads();

    {
        float bj = b2[colL];
#pragma unroll
        for (int t = 0; t < 4; ++t) acc[t] = (f32x4){bj, bj, bj, bj};
    }
    mfma_gemm64(Shi, Slo, whi, wlo, 6, lane, q, acc);
    __syncthreads();
#pragma unroll
    for (int t = 0; t < 4; ++t)
#pragma unroll
        for (int i = 0; i < 4; ++i) {
            int row = t * 16 + ((lane >> 4) << 2) + i;
            float vv = acc[t][i] + res[t * 4 + i];
            int grow = r0 + row;
            if (grow < N_NODES) h[(size_t)grow * 64 + colL] = vv;
            unsigned uh = bf16_1(vv);
            Shi[row * 72 + colL] = (ushort_t)uh;
            Slo[row * 72 + colL] = (ushort_t)bf16_1(vv - __uint_as_float(uh << 16));
        }
    __syncthreads();

    {
        float bj = m1b[colL];
#pragma unroll
        for (int t = 0; t < 4; ++t) acc[t] = (f32x4){bj, bj, bj, bj};
    }
    mfma_gemm64(Shi, Slo, whi, wlo, 7, lane, q, acc);
    __syncthreads();
    epi_S(acc, true, Shi, Slo, lane, colL);
    __syncthreads();

    {
        float bj = m2b[colL];
#pragma unroll
        for (int t = 0; t < 4; ++t) acc[t] = (f32x4){bj, bj, bj, bj};
    }
    mfma_gemm64(Shi, Slo, whi, wlo, 8, lane, q, acc);
#pragma unroll
    for (int t = 0; t < 4; ++t)
#pragma unroll
        for (int i = 0; i < 4; ++i) {
            int row = t * 16 + ((lane >> 4) << 2) + i;
            int grow = r0 + row;
            if (grow < N_NODES)
                msg16[(size_t)grow * 64 + colL] = (ushort_t)bf16_1(fmaxf(acc[t][i], 0.f));
        }
}

// ---- update layer1 then head precompute (MFMA) ----
__global__ __launch_bounds__(256, 2) void k_update_headpre(const float* __restrict__ h,
                                                           const float* __restrict__ agg,
                                                           const int* __restrict__ start,
                                                           const ushort_t* __restrict__ whi,
                                                           const ushort_t* __restrict__ wlo,
                                                           const float* __restrict__ b1,
                                                           const float* __restrict__ b2,
                                                           const float* __restrict__ h1w,
                                                           const float* __restrict__ hb1,
                                                           ushort_t* __restrict__ hA16,
                                                           ushort_t* __restrict__ hB16) {
    __shared__ ushort_t Shi[64 * 72];
    __shared__ ushort_t Slo[64 * 72];
    __shared__ float degS[64];
    const int tid = threadIdx.x;
    const int lane = tid & 63;
    const int q = __builtin_amdgcn_readfirstlane(tid >> 6);
    const int colL = q * 16 + (lane & 15);
    const int r0 = blockIdx.x * 64;
    const int nrows = min(64, N_NODES - r0);
    const int srow = tid >> 2, c0 = (tid & 3) * 16;
    const bool rv = srow < nrows;

    if (tid < 64) {
        int g = r0 + tid;
        degS[tid] = (g < N_NODES) ? (float)(start[g + 1] - start[g]) : 0.f;
    }
    __syncthreads();

    f32x4 acc[4];
    {
        float bj = b1[colL];
#pragma unroll
        for (int t = 0; t < 4; ++t) acc[t] = (f32x4){bj, bj, bj, bj};
    }
    float v[16];
    {
        float invS = rv ? (1.f / fmaxf(degS[srow], 1.f)) : 0.f;
        load16(agg + (size_t)(r0 + srow) * 64 + c0, rv, invS, v);
        split16_store(Shi, Slo, srow, c0, v);
    }
    __syncthreads();
    mfma_gemm64(Shi, Slo, whi, wlo, 10, lane, q, acc);
    __syncthreads();
    load16(h + (size_t)(r0 + srow) * 64 + c0, rv, 1.f, v);
    split16_store(Shi, Slo, srow, c0, v);
    __syncthreads();
    mfma_gemm64(Shi, Slo, whi, wlo, 9, lane, q, acc);
    float res[16];
#pragma unroll
    for (int t = 0; t < 4; ++t)
#pragma unroll
        for (int i = 0; i < 4; ++i) {
            int row = t * 16 + ((lane >> 4) << 2) + i;
            res[t * 4 + i] = bf16_f(Shi[row * 72 + colL]) + bf16_f(Slo[row * 72 + colL]);
        }
    __syncthreads();
    epi_S(acc, true, Shi, Slo, lane, colL);
    __syncthreads();

    {
        float bj = b2[colL];
#pragma unroll
        for (int t = 0; t < 4; ++t) acc[t] = (f32x4){bj, bj, bj, bj};
    }
    mfma_gemm64(Shi, Slo, whi, wlo, 11, lane, q, acc);
    __syncthreads();
#pragma unroll
    for (int t = 0; t < 4; ++t)
#pragma unroll
        for (int i = 0; i < 4; ++i) {
            int row = t * 16 + ((lane >> 4) << 2) + i;
            float vv = acc[t][i] + res[t * 4 + i];
            unsigned uh = bf16_1(vv);
            Shi[row * 72 + colL] = (ushort_t)uh;
            Slo[row * 72 + colL] = (ushort_t)bf16_1(vv - __uint_as_float(uh << 16));
        }
    __syncthreads();

    const float hb1c  = hb1[colL];
    const float w128c = h1w[128 * 64 + colL];
    const float w129c = h1w[129 * 64 + colL];

#pragma unroll
    for (int t = 0; t < 4; ++t)
#pragma unroll
        for (int i = 0; i < 4; ++i) {
            int row = t * 16 + ((lane >> 4) << 2) + i;
            acc[t][i] = hb1c + degS[row] * w128c;
        }
    mfma_gemm64(Shi, Slo, whi, wlo, 12, lane, q, acc);
#pragma unroll
    for (int t = 0; t < 4; ++t)
#pragma unroll
        for (int i = 0; i < 4; ++i) {
            int row = t * 16 + ((lane >> 4) << 2) + i;
            int grow = r0 + row;
            if (grow < N_NODES)
                hA16[(size_t)grow * 64 + colL] = (ushort_t)bf16_1(acc[t][i]);
        }

#pragma unroll
    for (int t = 0; t < 4; ++t)
#pragma unroll
        for (int i = 0; i < 4; ++i) {
            int row = t * 16 + ((lane >> 4) << 2) + i;
            acc[t][i] = degS[row] * w129c;
        }
    mfma_gemm64(Shi, Slo, whi, wlo, 13, lane, q, acc);
#pragma unroll
    for (int t = 0; t < 4; ++t)
#pragma unroll
        for (int i = 0; i < 4; ++i) {
            int row = t * 16 + ((lane >> 4) << 2) + i;
            int grow = r0 + row;
            if (grow < N_NODES)
                hB16[(size_t)grow * 64 + colL] = (ushort_t)bf16_1(acc[t][i]);
        }
}

// ------- out[e] = out[e+HALF] = softplus(relu(hA[src]+hB[dst]) . h2w + h2b) + 1e-6 ------
__global__ __launch_bounds__(256) void k_head(const int* __restrict__ rowIdx,
                                              const int* __restrict__ colIdx,
                                              const ushort_t* __restrict__ hA16,
                                              const ushort_t* __restrict__ hB16,
                                              const float* __restrict__ w2,
                                              const float* __restrict__ b2,
                                              float* __restrict__ out) {
    const int lane = threadIdx.x & 63;
    const int sub = lane & 15;
    const int grp = lane >> 4;
    const int waveId = (blockIdx.x * 256 + threadIdx.x) >> 6;
    const int step = gridDim.x * 4 * 4;
    const float4 wv = *(const float4*)(w2 + sub * 4);
    const float b2v = b2[0];
    for (int e = waveId * 4 + grp; e < HALF_E; e += step) {
        int s = rowIdx[e];
        int d = colIdx[e];
        ushort4 a4 = *(const ushort4*)(hA16 + (size_t)s * 64 + sub * 4);
        ushort4 b4 = *(const ushort4*)(hB16 + (size_t)d * 64 + sub * 4);
        float t0 = fmaxf(bf16_f(a4.x) + bf16_f(b4.x), 0.0f);
        float t1 = fmaxf(bf16_f(a4.y) + bf16_f(b4.y), 0.0f);
        float t2 = fmaxf(bf16_f(a4.z) + bf16_f(b4.z), 0.0f);
        float t3 = fmaxf(bf16_f(a4.w) + bf16_f(b4.w), 0.0f);
        float p = t0 * wv.x + t1 * wv.y + t2 * wv.z + t3 * wv.w;
        p += __shfl_xor(p, 1);
        p += __shfl_xor(p, 2);
        p += __shfl_xor(p, 4);
        p += __shfl_xor(p, 8);
        if (sub == 0) {
            float sv = p + b2v;
            float sp = fmaxf(sv, 0.0f) + log1pf(expf(-fabsf(sv)));
            float wvv = sp + 1e-6f;
            out[e] = wvv;
            out[e + HALF_E] = wvv;
        }
    }
}

extern "C" void kernel_launch(void* const* d_in, const int* in_sizes, int n_in,
                              void* d_out, int out_size, void* d_ws, size_t ws_size,
                              hipStream_t stream) {
    const float* x      = (const float*)d_in[0];
    const int*   rowIdx = (const int*)d_in[1];
    const int*   colIdx = rowIdx + E_EDGES;
    const float* w_in   = (const float*)d_in[2];
    const float* b_in   = (const float*)d_in[3];
    const float* l0_m1w = (const float*)d_in[4];
    const float* l0_m1b = (const float*)d_in[5];
    const float* l0_m2w = (const float*)d_in[6];
    const float* l0_m2b = (const float*)d_in[7];
    const float* l0_u1w = (const float*)d_in[8];
    const float* l0_u1b = (const float*)d_in[9];
    const float* l0_u2w = (const float*)d_in[10];
    const float* l0_u2b = (const float*)d_in[11];
    const float* l1_m1w = (const float*)d_in[12];
    const float* l1_m1b = (const float*)d_in[13];
    const float* l1_m2w = (const float*)d_in[14];
    const float* l1_m2b = (const float*)d_in[15];
    const float* l1_u1w = (const float*)d_in[16];
    const float* l1_u1b = (const float*)d_in[17];
    const float* l1_u2w = (const float*)d_in[18];
    const float* l1_u2b = (const float*)d_in[19];
    const float* h1w    = (const float*)d_in[20];
    const float* h1b    = (const float*)d_in[21];
    const float* h2w    = (const float*)d_in[22];
    const float* h2b    = (const float*)d_in[23];

    float* out = (float*)d_out;

    float*    h     = (float*)d_ws;                         // N x 64 f32
    float*    agg   = h + (size_t)N_NODES * 64;             // N x 64 f32
    ushort_t* msg16 = (ushort_t*)(agg + (size_t)N_NODES * 64); // N x 64 bf16
    ushort_t* hB16  = msg16 + (size_t)N_NODES * 64;         // N x 64 bf16
    int*      start = (int*)(hB16 + (size_t)N_NODES * 64);  // N + 1
    int*      part  = start + N_NODES + 1;                  // 256*256 partial hist
    int*      bbase = part + NBH_BLOCKS * NBUCK;            // 257 (pad 32)
    int*      curA  = bbase + NBUCK + 32;                   // 256
    int*      csr   = curA + NBUCK;                         // E
    ushort_t* whi   = (ushort_t*)(csr + E_EDGES);           // 14*4096 bf16
    ushort_t* wlo   = whi + 14 * 4096;                      // 14*4096 bf16
    uint2*    pairs = (uint2*)agg;                          // alias: dead before gather writes agg
    ushort_t* hA16  = msg16;                                // alias: msg16 dead after gather1

    const int nb64 = (N_NODES + 63) / 64;                   // 1563 blocks for MLP kernels
    const int gatherBlocks = (N_NODES + 3) / 4;

    // ---- CSR build + weight split ----
    k_bhist<<<NBH_BLOCKS, 256, 0, stream>>>(rowIdx, part);
    k_bscan256<<<1, 256, 0, stream>>>(part, bbase, curA, start);
    k_bucketA<<<NBLK_A, 256, 0, stream>>>(rowIdx, colIdx, curA, pairs);
    k_bucketB<<<NBUCK, 256, 0, stream>>>(bbase, pairs, start, csr);
    k_wsplit<<<14, 512, 0, stream>>>(w_in, l0_m1w, l0_m2w, l0_u1w, l0_u2w,
                                     l1_m1w, l1_m2w, l1_u1w, l1_u2w, h1w, whi, wlo);

    // ---- input linear + layer0 message ----
    k_lin_msg<<<nb64, 256, 0, stream>>>(x, whi, wlo, b_in, l0_m1b, l0_m2b, h, msg16);
    // ---- layer 0 ----
    k_gather<<<gatherBlocks, 256, 0, stream>>>(start, csr, msg16, agg);
    k_update_msg<<<nb64, 256, 0, stream>>>(h, agg, start, whi, wlo,
                                           l0_u1b, l0_u2b, l1_m1b, l1_m2b, msg16);
    // ---- layer 1 ----
    k_gather<<<gatherBlocks, 256, 0, stream>>>(start, csr, msg16, agg);
    k_update_headpre<<<nb64, 256, 0, stream>>>(h, agg, start, whi, wlo,
                                               l1_u1b, l1_u2b, h1w, h1b, hA16, hB16);
    // ---- head ----
    k_head<<<4096, 256, 0, stream>>>(rowIdx, colIdx, hA16, hB16, h2w, h2b, out);
}

// Round 14
// 255.146 us; speedup vs baseline: 1.9504x; 1.1003x over previous
//
#include <hip/hip_runtime.h>
#include <math.h>

#define N_NODES 100000
#define E_EDGES 1600000
#define HALF_E  (E_EDGES / 2)

#define NBUCK 256
#define ROWS_PER_BUCKET ((N_NODES + NBUCK - 1) / NBUCK)   // 391
#define EDGES_PER_BLK_A 4096
#define NBLK_A ((E_EDGES + EDGES_PER_BLK_A - 1) / EDGES_PER_BLK_A)  // 391
#define NBH_BLOCKS 256

typedef unsigned short ushort_t;
typedef __attribute__((ext_vector_type(8))) short bf16x8;
typedef __attribute__((ext_vector_type(8))) unsigned short u16x8;
typedef __attribute__((ext_vector_type(4))) float f32x4;

#define MFMA16(a, b, c) __builtin_amdgcn_mfma_f32_16x16x32_bf16(a, b, c, 0, 0, 0)

// ---- bf16 helpers (RNE pack, cheap unpack) ----
__device__ __forceinline__ unsigned bf16_1(float f) {
    unsigned u = __float_as_uint(f);
    return (u + 0x7fffu + ((u >> 16) & 1u)) >> 16;
}
__device__ __forceinline__ float bf16_f(ushort_t us) {
    return __uint_as_float(((unsigned)us) << 16);
}

// ============ CSR build (bucketed) ============

__global__ __launch_bounds__(256) void k_bhist(const int* __restrict__ rowIdx,
                                               int* __restrict__ part) {
    __shared__ int c[NBUCK];
    const int tid = threadIdx.x;
    c[tid] = 0;
    __syncthreads();
    for (int e = blockIdx.x * 256 + tid; e < E_EDGES; e += NBH_BLOCKS * 256)
        atomicAdd(&c[rowIdx[e] / ROWS_PER_BUCKET], 1);
    __syncthreads();
    part[blockIdx.x * NBUCK + tid] = c[tid];
}

__global__ __launch_bounds__(256) void k_bscan256(const int* __restrict__ part,
                                                  int* __restrict__ bbase,
                                                  int* __restrict__ curA,
                                                  int* __restrict__ start) {
    __shared__ int sc[NBUCK];
    const int tid = threadIdx.x;
    int v = 0;
    for (int b = 0; b < NBH_BLOCKS; ++b) v += part[b * NBUCK + tid];
    sc[tid] = v;
    __syncthreads();
    for (int st = 1; st < 256; st <<= 1) {
        int t = (tid >= st) ? sc[tid - st] : 0;
        __syncthreads();
        sc[tid] += t;
        __syncthreads();
    }
    int excl = sc[tid] - v;
    bbase[tid] = excl;
    curA[tid] = excl;
    if (tid == 255) bbase[256] = sc[255];
    if (tid == 0) start[N_NODES] = E_EDGES;
}

__global__ __launch_bounds__(256) void k_bucketA(const int* __restrict__ rowIdx,
                                                 const int* __restrict__ colIdx,
                                                 int* __restrict__ cursorA,
                                                 uint2* __restrict__ pairs) {
    __shared__ uint2 stage[EDGES_PER_BLK_A];
    __shared__ unsigned char bmap[EDGES_PER_BLK_A];
    __shared__ int cntL[NBUCK], scanEx[NBUCK], cur[NBUCK], posG[NBUCK];
    const int tid = threadIdx.x;
    const int e0 = blockIdx.x * EDGES_PER_BLK_A;
    const int n = min(EDGES_PER_BLK_A, E_EDGES - e0);

    cntL[tid] = 0;
    __syncthreads();
    for (int i = tid; i < n; i += 256) {
        int b = rowIdx[e0 + i] / ROWS_PER_BUCKET;
        atomicAdd(&cntL[b], 1);
    }
    __syncthreads();
    int myc = cntL[tid];
    scanEx[tid] = myc;
    __syncthreads();
    for (int st = 1; st < 256; st <<= 1) {
        int t = (tid >= st) ? scanEx[tid - st] : 0;
        __syncthreads();
        scanEx[tid] += t;
        __syncthreads();
    }
    int ex = scanEx[tid] - myc;
    __syncthreads();
    scanEx[tid] = ex;
    cur[tid] = ex;
    if (myc) posG[tid] = atomicAdd(&cursorA[tid], myc);
    __syncthreads();
    for (int i = tid; i < n; i += 256) {
        int r = rowIdx[e0 + i];
        int c = colIdx[e0 + i];
        int b = r / ROWS_PER_BUCKET;
        int slot = atomicAdd(&cur[b], 1);
        stage[slot] = make_uint2((unsigned)c, (unsigned)r);
        bmap[slot] = (unsigned char)b;
    }
    __syncthreads();
    for (int i = tid; i < n; i += 256) {
        int b = bmap[i];
        int dst = posG[b] + (i - scanEx[b]);
        pairs[dst] = stage[i];
    }
}

__global__ __launch_bounds__(256) void k_bucketB(const int* __restrict__ bbase,
                                                 const uint2* __restrict__ pairs,
                                                 int* __restrict__ start,
                                                 int* __restrict__ csr) {
    __shared__ int cur[ROWS_PER_BUCKET];
    __shared__ int scn[512];
    const int tid = threadIdx.x;
    const int rowbase = blockIdx.x * ROWS_PER_BUCKET;
    const int nrows = min(ROWS_PER_BUCKET, N_NODES - rowbase);
    for (int i = tid; i < nrows; i += 256) cur[i] = 0;
    __syncthreads();
    const int bBeg = bbase[blockIdx.x];
    const int bEnd = bbase[blockIdx.x + 1];
    for (int i = bBeg + tid; i < bEnd; i += 256)
        atomicAdd(&cur[(int)pairs[i].y - rowbase], 1);
    __syncthreads();
    scn[tid] = (tid < nrows) ? cur[tid] : 0;
    scn[tid + 256] = (tid + 256 < nrows) ? cur[tid + 256] : 0;
    __syncthreads();
    for (int st = 1; st < 512; st <<= 1) {
        int i0 = tid, i1 = tid + 256;
        int t0 = (i0 >= st) ? scn[i0 - st] : 0;
        int t1 = (i1 >= st) ? scn[i1 - st] : 0;
        __syncthreads();
        scn[i0] += t0;
        scn[i1] += t1;
        __syncthreads();
    }
    for (int i = tid; i < nrows; i += 256) {
        int sv = bBeg + scn[i] - cur[i];
        start[rowbase + i] = sv;
        cur[i] = sv;
    }
    __syncthreads();
    for (int i = bBeg + tid; i < bEnd; i += 256) {
        uint2 p = pairs[i];
        int pos = atomicAdd(&cur[(int)p.y - rowbase], 1);
        csr[pos] = (int)p.x;
    }
}

// ============ weight split (fp32 -> fragment-layout bf16 hi/lo) ============
__global__ __launch_bounds__(512) void k_wsplit(const float* __restrict__ w_in,
                                                const float* __restrict__ l0_m1w,
                                                const float* __restrict__ l0_m2w,
                                                const float* __restrict__ l0_u1w,
                                                const float* __restrict__ l0_u2w,
                                                const float* __restrict__ l1_m1w,
                                                const float* __restrict__ l1_m2w,
                                                const float* __restrict__ l1_u1w,
                                                const float* __restrict__ l1_u2w,
                                                const float* __restrict__ h1w,
                                                ushort_t* __restrict__ whi,
                                                ushort_t* __restrict__ wlo) {
    const float* src;
    switch (blockIdx.x) {
        case 0:  src = w_in;           break;
        case 1:  src = w_in + 4096;    break;
        case 2:  src = l0_m1w;         break;
        case 3:  src = l0_m2w;         break;
        case 4:  src = l0_u1w;         break;
        case 5:  src = l0_u1w + 4096;  break;
        case 6:  src = l0_u2w;         break;
        case 7:  src = l1_m1w;         break;
        case 8:  src = l1_m2w;         break;
        case 9:  src = l1_u1w;         break;
        case 10: src = l1_u1w + 4096;  break;
        case 11: src = l1_u2w;         break;
        case 12: src = h1w;            break;
        default: src = h1w + 4096;     break;
    }
    const int tid = threadIdx.x;
    const int h = tid >> 8;
    const int c = (tid >> 6) & 3;
    const int lane = tid & 63;
    const int kg = lane >> 4, lr = lane & 15;
    const int col = c * 16 + lr;
    u16x8 hi8, lo8;
#pragma unroll
    for (int j = 0; j < 8; ++j) {
        int k = h * 32 + kg * 8 + j;
        float v = src[k * 64 + col];
        unsigned uh = bf16_1(v);
        hi8[j] = (unsigned short)uh;
        lo8[j] = (unsigned short)bf16_1(v - __uint_as_float(uh << 16));
    }
    size_t idx = (size_t)blockIdx.x * 4096 + ((size_t)(h * 4 + c) * 64 + lane) * 8;
    *(u16x8*)(whi + idx) = hi8;
    *(u16x8*)(wlo + idx) = lo8;
}

// ============ MFMA node-MLP machinery ============

__device__ __forceinline__ void mfma_gemm64(const ushort_t* Shi, const ushort_t* Slo,
                                            const ushort_t* __restrict__ whi,
                                            const ushort_t* __restrict__ wlo,
                                            int panel, int lane, int q, f32x4 acc[4]) {
    const ushort_t* WH = whi + (size_t)panel * 4096;
    const ushort_t* WL = wlo + (size_t)panel * 4096;
    const int f0 = (q * 64 + lane) * 8;
    const int f1 = ((4 + q) * 64 + lane) * 8;
    bf16x8 bh0 = *(const bf16x8*)(WH + f0);
    bf16x8 bh1 = *(const bf16x8*)(WH + f1);
    bf16x8 bl0 = *(const bf16x8*)(WL + f0);
    bf16x8 bl1 = *(const bf16x8*)(WL + f1);
    const int ar = (lane & 15) * 72 + ((lane >> 4) << 3);
#pragma unroll
    for (int t = 0; t < 4; ++t) {
        const ushort_t* a  = Shi + t * 16 * 72 + ar;
        const ushort_t* al = Slo + t * 16 * 72 + ar;
        bf16x8 ah0 = *(const bf16x8*)(a);
        bf16x8 ah1 = *(const bf16x8*)(a + 32);
        bf16x8 aL0 = *(const bf16x8*)(al);
        bf16x8 aL1 = *(const bf16x8*)(al + 32);
        acc[t] = MFMA16(ah0, bh0, acc[t]);
        acc[t] = MFMA16(ah1, bh1, acc[t]);
        acc[t] = MFMA16(ah0, bl0, acc[t]);
        acc[t] = MFMA16(aL0, bh0, acc[t]);
        acc[t] = MFMA16(ah1, bl1, acc[t]);
        acc[t] = MFMA16(aL1, bh1, acc[t]);
    }
}

__device__ __forceinline__ void load16(const float* src, bool valid, float scale,
                                       float v[16]) {
#pragma unroll
    for (int j4 = 0; j4 < 4; ++j4) {
        float4 t = valid ? *(const float4*)(src + j4 * 4) : make_float4(0.f, 0.f, 0.f, 0.f);
        v[j4 * 4 + 0] = t.x * scale;
        v[j4 * 4 + 1] = t.y * scale;
        v[j4 * 4 + 2] = t.z * scale;
        v[j4 * 4 + 3] = t.w * scale;
    }
}

__device__ __forceinline__ void split16_store(ushort_t* Shi, ushort_t* Slo,
                                              int row, int c0, const float v[16]) {
    u16x8 ha, la, hb, lb;
#pragma unroll
    for (int j = 0; j < 8; ++j) {
        unsigned uh = bf16_1(v[j]);
        ha[j] = (unsigned short)uh;
        la[j] = (unsigned short)bf16_1(v[j] - __uint_as_float(uh << 16));
    }
#pragma unroll
    for (int j = 0; j < 8; ++j) {
        unsigned uh = bf16_1(v[8 + j]);
        hb[j] = (unsigned short)uh;
        lb[j] = (unsigned short)bf16_1(v[8 + j] - __uint_as_float(uh << 16));
    }
    *(u16x8*)(Shi + row * 72 + c0) = ha;
    *(u16x8*)(Shi + row * 72 + c0 + 8) = hb;
    *(u16x8*)(Slo + row * 72 + c0) = la;
    *(u16x8*)(Slo + row * 72 + c0 + 8) = lb;
}

__device__ __forceinline__ void epi_S(const f32x4 acc[4], bool relu,
                                      ushort_t* Shi, ushort_t* Slo,
                                      int lane, int colL) {
#pragma unroll
    for (int t = 0; t < 4; ++t)
#pragma unroll
        for (int i = 0; i < 4; ++i) {
            int row = t * 16 + ((lane >> 4) << 2) + i;
            float vv = acc[t][i];
            if (relu) vv = fmaxf(vv, 0.f);
            unsigned uh = bf16_1(vv);
            Shi[row * 72 + colL] = (ushort_t)uh;
            Slo[row * 72 + colL] = (ushort_t)bf16_1(vv - __uint_as_float(uh << 16));
        }
}

// h = x@w_in+b_in ; msg16 = relu(relu(h@m1+b1)@m2+b2)
__global__ __launch_bounds__(256, 4) void k_lin_msg(const float* __restrict__ x,
                                                    const ushort_t* __restrict__ whi,
                                                    const ushort_t* __restrict__ wlo,
                                                    const float* __restrict__ b_in,
                                                    const float* __restrict__ m1b,
                                                    const float* __restrict__ m2b,
                                                    float* __restrict__ h,
                                                    ushort_t* __restrict__ msg16) {
    __shared__ ushort_t Shi[64 * 72];
    __shared__ ushort_t Slo[64 * 72];
    const int tid = threadIdx.x;
    const int lane = tid & 63;
    const int q = __builtin_amdgcn_readfirstlane(tid >> 6);
    const int colL = q * 16 + (lane & 15);
    const int r0 = blockIdx.x * 64;
    const int nrows = min(64, N_NODES - r0);
    const int srow = tid >> 2, c0 = (tid & 3) * 16;
    const bool rv = srow < nrows;

    f32x4 acc[4];
    {
        float bj = b_in[colL];
#pragma unroll
        for (int t = 0; t < 4; ++t) acc[t] = (f32x4){bj, bj, bj, bj};
    }
    float v[16];
    load16(x + (size_t)(r0 + srow) * 128 + c0, rv, 1.f, v);
    split16_store(Shi, Slo, srow, c0, v);
    __syncthreads();
    mfma_gemm64(Shi, Slo, whi, wlo, 0, lane, q, acc);
    __syncthreads();
    load16(x + (size_t)(r0 + srow) * 128 + 64 + c0, rv, 1.f, v);
    split16_store(Shi, Slo, srow, c0, v);
    __syncthreads();
    mfma_gemm64(Shi, Slo, whi, wlo, 1, lane, q, acc);
    __syncthreads();
#pragma unroll
    for (int t = 0; t < 4; ++t)
#pragma unroll
        for (int i = 0; i < 4; ++i) {
            int row = t * 16 + ((lane >> 4) << 2) + i;
            int grow = r0 + row;
            if (grow < N_NODES) h[(size_t)grow * 64 + colL] = acc[t][i];
        }
    epi_S(acc, false, Shi, Slo, lane, colL);
    __syncthreads();

    {
        float bj = m1b[colL];
#pragma unroll
        for (int t = 0; t < 4; ++t) acc[t] = (f32x4){bj, bj, bj, bj};
    }
    mfma_gemm64(Shi, Slo, whi, wlo, 2, lane, q, acc);
    __syncthreads();
    epi_S(acc, true, Shi, Slo, lane, colL);
    __syncthreads();

    {
        float bj = m2b[colL];
#pragma unroll
        for (int t = 0; t < 4; ++t) acc[t] = (f32x4){bj, bj, bj, bj};
    }
    mfma_gemm64(Shi, Slo, whi, wlo, 3, lane, q, acc);
#pragma unroll
    for (int t = 0; t < 4; ++t)
#pragma unroll
        for (int i = 0; i < 4; ++i) {
            int row = t * 16 + ((lane >> 4) << 2) + i;
            int grow = r0 + row;
            if (grow < N_NODES)
                msg16[(size_t)grow * 64 + colL] = (ushort_t)bf16_1(fmaxf(acc[t][i], 0.f));
        }
}

// ============ aggregation: gather, 8 edges per VMEM instruction ============
// lane = (edge-slot g8 = lane>>3, 16B slice s8 = lane&7); u16x8 loads.
__global__ __launch_bounds__(256) void k_gather(const int* __restrict__ start,
                                                const int* __restrict__ csr,
                                                const ushort_t* __restrict__ msg16,
                                                float* __restrict__ agg) {
    const int lane = threadIdx.x & 63;
    const int wid  = threadIdx.x >> 6;
    const int g8   = lane >> 3;
    const int s8   = lane & 7;
    int r = blockIdx.x * 4 + wid;
    if (r >= N_NODES) return;
    int b = start[r];
    int e0 = start[r + 1];
    float a[8] = {0.f, 0.f, 0.f, 0.f, 0.f, 0.f, 0.f, 0.f};
    for (int base = b; base < e0; base += 64) {
        int n = e0 - base;
        if (n > 64) n = 64;
        int c = 0;
        if (base + lane < e0) c = csr[base + lane];
        for (int j = 0; j < n; j += 8) {
            int jj = j + g8;
            bool act = jj < n;
            int cj = __shfl(c, act ? jj : 0, 64);
            u16x8 v = *(const u16x8*)(msg16 + (size_t)cj * 64 + s8 * 8);
            if (act) {
#pragma unroll
                for (int k = 0; k < 8; ++k) a[k] += bf16_f((ushort_t)v[k]);
            }
        }
    }
#pragma unroll
    for (int k = 0; k < 8; ++k) {
        a[k] += __shfl_xor(a[k], 8, 64);
        a[k] += __shfl_xor(a[k], 16, 64);
        a[k] += __shfl_xor(a[k], 32, 64);
    }
    if (g8 == 0) {
        float* dst = agg + (size_t)r * 64 + s8 * 8;
        *(float4*)(dst)     = make_float4(a[0], a[1], a[2], a[3]);
        *(float4*)(dst + 4) = make_float4(a[4], a[5], a[6], a[7]);
    }
}

// ---- update layer0 then msg layer1 (MFMA) ----
__global__ __launch_bounds__(256, 4) void k_update_msg(float* __restrict__ h,
                                                       const float* __restrict__ agg,
                                                       const int* __restrict__ start,
                                                       const ushort_t* __restrict__ whi,
                                                       const ushort_t* __restrict__ wlo,
                                                       const float* __restrict__ b1,
                                                       const float* __restrict__ b2,
                                                       const float* __restrict__ m1b,
                                                       const float* __restrict__ m2b,
                                                       ushort_t* __restrict__ msg16) {
    __shared__ ushort_t Shi[64 * 72];
    __shared__ ushort_t Slo[64 * 72];
    const int tid = threadIdx.x;
    const int lane = tid & 63;
    const int q = __builtin_amdgcn_readfirstlane(tid >> 6);
    const int colL = q * 16 + (lane & 15);
    const int r0 = blockIdx.x * 64;
    const int nrows = min(64, N_NODES - r0);
    const int srow = tid >> 2, c0 = (tid & 3) * 16;
    const bool rv = srow < nrows;

    f32x4 acc[4];
    {
        float bj = b1[colL];
#pragma unroll
        for (int t = 0; t < 4; ++t) acc[t] = (f32x4){bj, bj, bj, bj};
    }
    float v[16];
    {
        float invS = 0.f;
        if (rv) {
            int g = r0 + srow;
            invS = 1.f / fmaxf((float)(start[g + 1] - start[g]), 1.f);
        }
        load16(agg + (size_t)(r0 + srow) * 64 + c0, rv, invS, v);
        split16_store(Shi, Slo, srow, c0, v);
    }
    __syncthreads();
    mfma_gemm64(Shi, Slo, whi, wlo, 5, lane, q, acc);
    __syncthreads();
    load16(h + (size_t)(r0 + srow) * 64 + c0, rv, 1.f, v);
    split16_store(Shi, Slo, srow, c0, v);
    __syncthreads();
    mfma_gemm64(Shi, Slo, whi, wlo, 4, lane, q, acc);
    float res[16];
#pragma unroll
    for (int t = 0; t < 4; ++t)
#pragma unroll
        for (int i = 0; i < 4; ++i) {
            int row = t * 16 + ((lane >> 4) << 2) + i;
            res[t * 4 + i] = bf16_f(Shi[row * 72 + colL]) + bf16_f(Slo[row * 72 + colL]);
        }
    __syncthreads();
    epi_S(acc, true, Shi, Slo, lane, colL);
    __syncthreads();

    {
        float bj = b2[colL];
#pragma unroll
        for (int t = 0; t < 4; ++t) acc[t] = (f32x4){bj, bj, bj, bj};
    }
    mfma_gemm64(Shi, Slo, whi, wlo, 6, lane, q, acc);
    __syncthreads();
#pragma unroll
    for (int t = 0; t < 4; ++t)
#pragma unroll
        for (int i = 0; i < 4; ++i) {
            int row = t * 16 + ((lane >> 4) << 2) + i;
            float vv = acc[t][i] + res[t * 4 + i];
            int grow = r0 + row;
            if (grow < N_NODES) h[(size_t)grow * 64 + colL] = vv;
            unsigned uh = bf16_1(vv);
            Shi[row * 72 + colL] = (ushort_t)uh;
            Slo[row * 72 + colL] = (ushort_t)bf16_1(vv - __uint_as_float(uh << 16));
        }
    __syncthreads();

    {
        float bj = m1b[colL];
#pragma unroll
        for (int t = 0; t < 4; ++t) acc[t] = (f32x4){bj, bj, bj, bj};
    }
    mfma_gemm64(Shi, Slo, whi, wlo, 7, lane, q, acc);
    __syncthreads();
    epi_S(acc, true, Shi, Slo, lane, colL);
    __syncthreads();

    {
        float bj = m2b[colL];
#pragma unroll
        for (int t = 0; t < 4; ++t) acc[t] = (f32x4){bj, bj, bj, bj};
    }
    mfma_gemm64(Shi, Slo, whi, wlo, 8, lane, q, acc);
#pragma unroll
    for (int t = 0; t < 4; ++t)
#pragma unroll
        for (int i = 0; i < 4; ++i) {
            int row = t * 16 + ((lane >> 4) << 2) + i;
            int grow = r0 + row;
            if (grow < N_NODES)
                msg16[(size_t)grow * 64 + colL] = (ushort_t)bf16_1(fmaxf(acc[t][i], 0.f));
        }
}

// ---- update layer1 then head precompute (MFMA) ----
__global__ __launch_bounds__(256, 4) void k_update_headpre(const float* __restrict__ h,
                                                           const float* __restrict__ agg,
                                                           const int* __restrict__ start,
                                                           const ushort_t* __restrict__ whi,
                                                           const ushort_t* __restrict__ wlo,
                                                           const float* __restrict__ b1,
                                                           const float* __restrict__ b2,
                                                           const float* __restrict__ h1w,
                                                           const float* __restrict__ hb1,
                                                           ushort_t* __restrict__ hA16,
                                                           ushort_t* __restrict__ hB16) {
    __shared__ ushort_t Shi[64 * 72];
    __shared__ ushort_t Slo[64 * 72];
    __shared__ float degS[64];
    const int tid = threadIdx.x;
    const int lane = tid & 63;
    const int q = __builtin_amdgcn_readfirstlane(tid >> 6);
    const int colL = q * 16 + (lane & 15);
    const int r0 = blockIdx.x * 64;
    const int nrows = min(64, N_NODES - r0);
    const int srow = tid >> 2, c0 = (tid & 3) * 16;
    const bool rv = srow < nrows;

    if (tid < 64) {
        int g = r0 + tid;
        degS[tid] = (g < N_NODES) ? (float)(start[g + 1] - start[g]) : 0.f;
    }
    __syncthreads();

    f32x4 acc[4];
    {
        float bj = b1[colL];
#pragma unroll
        for (int t = 0; t < 4; ++t) acc[t] = (f32x4){bj, bj, bj, bj};
    }
    float v[16];
    {
        float invS = rv ? (1.f / fmaxf(degS[srow], 1.f)) : 0.f;
        load16(agg + (size_t)(r0 + srow) * 64 + c0, rv, invS, v);
        split16_store(Shi, Slo, srow, c0, v);
    }
    __syncthreads();
    mfma_gemm64(Shi, Slo, whi, wlo, 10, lane, q, acc);
    __syncthreads();
    load16(h + (size_t)(r0 + srow) * 64 + c0, rv, 1.f, v);
    split16_store(Shi, Slo, srow, c0, v);
    __syncthreads();
    mfma_gemm64(Shi, Slo, whi, wlo, 9, lane, q, acc);
    float res[16];
#pragma unroll
    for (int t = 0; t < 4; ++t)
#pragma unroll
        for (int i = 0; i < 4; ++i) {
            int row = t * 16 + ((lane >> 4) << 2) + i;
            res[t * 4 + i] = bf16_f(Shi[row * 72 + colL]) + bf16_f(Slo[row * 72 + colL]);
        }
    __syncthreads();
    epi_S(acc, true, Shi, Slo, lane, colL);
    __syncthreads();

    {
        float bj = b2[colL];
#pragma unroll
        for (int t = 0; t < 4; ++t) acc[t] = (f32x4){bj, bj, bj, bj};
    }
    mfma_gemm64(Shi, Slo, whi, wlo, 11, lane, q, acc);
    __syncthreads();
#pragma unroll
    for (int t = 0; t < 4; ++t)
#pragma unroll
        for (int i = 0; i < 4; ++i) {
            int row = t * 16 + ((lane >> 4) << 2) + i;
            float vv = acc[t][i] + res[t * 4 + i];
            unsigned uh = bf16_1(vv);
            Shi[row * 72 + colL] = (ushort_t)uh;
            Slo[row * 72 + colL] = (ushort_t)bf16_1(vv - __uint_as_float(uh << 16));
        }
    __syncthreads();

    const float hb1c  = hb1[colL];
    const float w128c = h1w[128 * 64 + colL];
    const float w129c = h1w[129 * 64 + colL];

#pragma unroll
    for (int t = 0; t < 4; ++t)
#pragma unroll
        for (int i = 0; i < 4; ++i) {
            int row = t * 16 + ((lane >> 4) << 2) + i;
            acc[t][i] = hb1c + degS[row] * w128c;
        }
    mfma_gemm64(Shi, Slo, whi, wlo, 12, lane, q, acc);
#pragma unroll
    for (int t = 0; t < 4; ++t)
#pragma unroll
        for (int i = 0; i < 4; ++i) {
            int row = t * 16 + ((lane >> 4) << 2) + i;
            int grow = r0 + row;
            if (grow < N_NODES)
                hA16[(size_t)grow * 64 + colL] = (ushort_t)bf16_1(acc[t][i]);
        }

#pragma unroll
    for (int t = 0; t < 4; ++t)
#pragma unroll
        for (int i = 0; i < 4; ++i) {
            int row = t * 16 + ((lane >> 4) << 2) + i;
            acc[t][i] = degS[row] * w129c;
        }
    mfma_gemm64(Shi, Slo, whi, wlo, 13, lane, q, acc);
#pragma unroll
    for (int t = 0; t < 4; ++t)
#pragma unroll
        for (int i = 0; i < 4; ++i) {
            int row = t * 16 + ((lane >> 4) << 2) + i;
            int grow = r0 + row;
            if (grow < N_NODES)
                hB16[(size_t)grow * 64 + colL] = (ushort_t)bf16_1(acc[t][i]);
        }
}

// ------- out[e] = out[e+HALF] = softplus(relu(hA[src]+hB[dst]) . h2w + h2b) + 1e-6 ------
// 8 lanes per edge, u16x8 (16B) gathers.
__global__ __launch_bounds__(256) void k_head(const int* __restrict__ rowIdx,
                                              const int* __restrict__ colIdx,
                                              const ushort_t* __restrict__ hA16,
                                              const ushort_t* __restrict__ hB16,
                                              const float* __restrict__ w2,
                                              const float* __restrict__ b2,
                                              float* __restrict__ out) {
    const int lane = threadIdx.x & 63;
    const int sub = lane & 7;
    const int grp = lane >> 3;
    const int waveId = (blockIdx.x * 256 + threadIdx.x) >> 6;
    const int step = gridDim.x * 4 * 8;
    float w2v[8];
    {
        float4 wa = *(const float4*)(w2 + sub * 8);
        float4 wb = *(const float4*)(w2 + sub * 8 + 4);
        w2v[0] = wa.x; w2v[1] = wa.y; w2v[2] = wa.z; w2v[3] = wa.w;
        w2v[4] = wb.x; w2v[5] = wb.y; w2v[6] = wb.z; w2v[7] = wb.w;
    }
    const float b2v = b2[0];
    for (int e = waveId * 8 + grp; e < HALF_E; e += step) {
        int s = rowIdx[e];
        int d = colIdx[e];
        u16x8 a8 = *(const u16x8*)(hA16 + (size_t)s * 64 + sub * 8);
        u16x8 b8 = *(const u16x8*)(hB16 + (size_t)d * 64 + sub * 8);
        float p = 0.f;
#pragma unroll
        for (int k = 0; k < 8; ++k) {
            float t = bf16_f((ushort_t)a8[k]) + bf16_f((ushort_t)b8[k]);
            p = fmaf(fmaxf(t, 0.f), w2v[k], p);
        }
        p += __shfl_xor(p, 1);
        p += __shfl_xor(p, 2);
        p += __shfl_xor(p, 4);
        if (sub == 0) {
            float sv = p + b2v;
            float sp = fmaxf(sv, 0.0f) + log1pf(expf(-fabsf(sv)));
            float wvv = sp + 1e-6f;
            out[e] = wvv;
            out[e + HALF_E] = wvv;
        }
    }
}

extern "C" void kernel_launch(void* const* d_in, const int* in_sizes, int n_in,
                              void* d_out, int out_size, void* d_ws, size_t ws_size,
                              hipStream_t stream) {
    const float* x      = (const float*)d_in[0];
    const int*   rowIdx = (const int*)d_in[1];
    const int*   colIdx = rowIdx + E_EDGES;
    const float* w_in   = (const float*)d_in[2];
    const float* b_in   = (const float*)d_in[3];
    const float* l0_m1w = (const float*)d_in[4];
    const float* l0_m1b = (const float*)d_in[5];
    const float* l0_m2w = (const float*)d_in[6];
    const float* l0_m2b = (const float*)d_in[7];
    const float* l0_u1w = (const float*)d_in[8];
    const float* l0_u1b = (const float*)d_in[9];
    const float* l0_u2w = (const float*)d_in[10];
    const float* l0_u2b = (const float*)d_in[11];
    const float* l1_m1w = (const float*)d_in[12];
    const float* l1_m1b = (const float*)d_in[13];
    const float* l1_m2w = (const float*)d_in[14];
    const float* l1_m2b = (const float*)d_in[15];
    const float* l1_u1w = (const float*)d_in[16];
    const float* l1_u1b = (const float*)d_in[17];
    const float* l1_u2w = (const float*)d_in[18];
    const float* l1_u2b = (const float*)d_in[19];
    const float* h1w    = (const float*)d_in[20];
    const float* h1b    = (const float*)d_in[21];
    const float* h2w    = (const float*)d_in[22];
    const float* h2b    = (const float*)d_in[23];

    float* out = (float*)d_out;

    float*    h     = (float*)d_ws;                         // N x 64 f32
    float*    agg   = h + (size_t)N_NODES * 64;             // N x 64 f32
    ushort_t* msg16 = (ushort_t*)(agg + (size_t)N_NODES * 64); // N x 64 bf16
    ushort_t* hB16  = msg16 + (size_t)N_NODES * 64;         // N x 64 bf16
    int*      start = (int*)(hB16 + (size_t)N_NODES * 64);  // N + 1
    int*      part  = start + N_NODES + 1;                  // 256*256 partial hist
    int*      bbase = part + NBH_BLOCKS * NBUCK;            // 257 (pad 32)
    int*      curA  = bbase + NBUCK + 32;                   // 256
    int*      csr   = curA + NBUCK;                         // E
    ushort_t* whi   = (ushort_t*)(csr + E_EDGES);           // 14*4096 bf16
    ushort_t* wlo   = whi + 14 * 4096;                      // 14*4096 bf16
    uint2*    pairs = (uint2*)agg;                          // alias: dead before gather writes agg
    ushort_t* hA16  = msg16;                                // alias: msg16 dead after gather1

    const int nb64 = (N_NODES + 63) / 64;                   // 1563 blocks for MLP kernels
    const int gatherBlocks = (N_NODES + 3) / 4;

    // ---- CSR build + weight split ----
    k_bhist<<<NBH_BLOCKS, 256, 0, stream>>>(rowIdx, part);
    k_bscan256<<<1, 256, 0, stream>>>(part, bbase, curA, start);
    k_bucketA<<<NBLK_A, 256, 0, stream>>>(rowIdx, colIdx, curA, pairs);
    k_bucketB<<<NBUCK, 256, 0, stream>>>(bbase, pairs, start, csr);
    k_wsplit<<<14, 512, 0, stream>>>(w_in, l0_m1w, l0_m2w, l0_u1w, l0_u2w,
                                     l1_m1w, l1_m2w, l1_u1w, l1_u2w, h1w, whi, wlo);

    // ---- input linear + layer0 message ----
    k_lin_msg<<<nb64, 256, 0, stream>>>(x, whi, wlo, b_in, l0_m1b, l0_m2b, h, msg16);
    // ---- layer 0 ----
    k_gather<<<gatherBlocks, 256, 0, stream>>>(start, csr, msg16, agg);
    k_update_msg<<<nb64, 256, 0, stream>>>(h, agg, start, whi, wlo,
                                           l0_u1b, l0_u2b, l1_m1b, l1_m2b, msg16);
    // ---- layer 1 ----
    k_gather<<<gatherBlocks, 256, 0, stream>>>(start, csr, msg16, agg);
    k_update_headpre<<<nb64, 256, 0, stream>>>(h, agg, start, whi, wlo,
                                               l1_u1b, l1_u2b, h1w, h1b, hA16, hB16);
    // ---- head ----
    k_head<<<4096, 256, 0, stream>>>(rowIdx, colIdx, hA16, hB16, h2w, h2b, out);
}